// Round 11
// baseline (595.869 us; speedup 1.0000x reference)
//
#include <hip/hip_runtime.h>

typedef unsigned short u16;
typedef float f32x4 __attribute__((ext_vector_type(4)));
typedef u16   u16x4 __attribute__((ext_vector_type(4)));
typedef u16   u16x8 __attribute__((ext_vector_type(8)));
typedef __bf16 bf16x8 __attribute__((ext_vector_type(8)));

static __device__ __forceinline__ u16 f2bf(float x) {
    unsigned int u = __builtin_bit_cast(unsigned int, x);
    u = (u + 0x7FFFu + ((u >> 16) & 1u)) >> 16;
    return (u16)u;
}
static __device__ __forceinline__ float bf2f(u16 x) {
    unsigned int u = ((unsigned int)x) << 16;
    return __builtin_bit_cast(float, u);
}
static __device__ __forceinline__ bf16x8 as_bf(u16x8 v) { return __builtin_bit_cast(bf16x8, v); }

// async global->LDS, 16B per lane; LDS dest = wave-uniform base + lane*16
static __device__ __forceinline__ void gload16(const u16* g, u16* lds) {
    __builtin_amdgcn_global_load_lds(
        (const __attribute__((address_space(1))) void*)g,
        (__attribute__((address_space(3))) void*)lds,
        16, 0, 0);
}

#define KSCALE 0.045084220027780106f   /* log2(e)/32 */

// Stage a [128 x 64] bf16 tile into LDS via global_load_lds; read-side XOR
// swizzle baked into the per-lane GLOBAL address (linear dest + swz source).
#define STAGE_G2L(dst, src, stride, ROUNDS) do {                               \
    _Pragma("unroll") for (int i_ = 0; i_ < (ROUNDS); ++i_) {                  \
        int c_ = (i_ * 4 + w) * 64 + l;                                        \
        int row_ = c_ >> 3, c8_ = c_ & 7;                                      \
        gload16((src) + (size_t)row_ * (stride) + ((c8_ ^ (row_ & 7)) << 3),   \
                &(dst)[(i_ * 4 + w) * 512]);                                   \
    } } while (0)

// Stage a [128 x 64] tile from FP32 global, converting to bf16, with the
// same swizzled LDS image (proven in qkv_gemm since round 0).
#define STAGE_F2B(dst, src, stride) do {                                       \
    _Pragma("unroll") for (int i_ = 0; i_ < 4; ++i_) {                         \
        int cid_ = i_ * 256 + tid;                                             \
        int row_ = cid_ >> 3, c8_ = cid_ & 7;                                  \
        const float* s_ = (src) + (size_t)row_ * (stride) + c8_ * 8;           \
        f32x4 v0_ = *(const f32x4*)(s_);                                       \
        f32x4 v1_ = *(const f32x4*)(s_ + 4);                                   \
        u16x8 t_;                                                              \
        t_[0] = f2bf(v0_[0]); t_[1] = f2bf(v0_[1]);                            \
        t_[2] = f2bf(v0_[2]); t_[3] = f2bf(v0_[3]);                            \
        t_[4] = f2bf(v1_[0]); t_[5] = f2bf(v1_[1]);                            \
        t_[6] = f2bf(v1_[2]); t_[7] = f2bf(v1_[3]);                            \
        *(u16x8*)(&(dst)[row_ * 64 + ((c8_ ^ (row_ & 7)) << 3)]) = t_;         \
    } } while (0)

// ---------------------------------------------------------------------------
// Kernel 1: Wv [1024 d][1024 e] fp32 -> Wvt [1024 e][1024 d] bf16 (transpose)
// ---------------------------------------------------------------------------
__global__ __launch_bounds__(256) void wt_kernel(const float* __restrict__ Wv,
                                                 u16* __restrict__ Wvt) {
    __shared__ float tile[64][65];
    const int bx = blockIdx.x, by = blockIdx.y;
    const int tid = threadIdx.x;
#pragma unroll
    for (int i = 0; i < 16; ++i) {
        int idx = i * 256 + tid;
        int r = idx >> 6, c = idx & 63;
        tile[r][c] = Wv[(by * 64 + r) * 1024 + bx * 64 + c];
    }
    __syncthreads();
#pragma unroll
    for (int i = 0; i < 16; ++i) {
        int idx = i * 256 + tid;
        int r = idx >> 6, c = idx & 63;
        Wvt[(bx * 64 + r) * 1024 + by * 64 + c] = f2bf(tile[c][r]);
    }
}

// ---------------------------------------------------------------------------
// Kernel 2: Gt[d'][d] = sum_e Wk[d'][e] * Wq[d][e]  (= (Wq*Wk^T)^T, bf16).
// 1024x1024x1024, 64 blocks of 128x128; both operands conv-staged from fp32.
// ---------------------------------------------------------------------------
__global__ __launch_bounds__(256, 3) void g_gemm(const float* __restrict__ Wk,
                                                 const float* __restrict__ Wq,
                                                 u16* __restrict__ Gt) {
    __shared__ u16 As[128 * 64];
    __shared__ u16 Bs[128 * 64];
    const int bid = blockIdx.x;
    const int bm = bid >> 3, bn = bid & 7;
    const int tid = threadIdx.x;
    const int w = tid >> 6, l = tid & 63, lg = l >> 4, lr = l & 15;
    const int wr = w >> 1, wc = w & 1;

    const f32x4 z4 = {0.f, 0.f, 0.f, 0.f};
    f32x4 acc[4][4];
#pragma unroll
    for (int m = 0; m < 4; ++m)
#pragma unroll
        for (int n = 0; n < 4; ++n) acc[m][n] = z4;

    for (int kb = 0; kb < 16; ++kb) {
        __syncthreads();
        STAGE_F2B(As, Wk + (size_t)(bm * 128) * 1024 + kb * 64, 1024);
        STAGE_F2B(Bs, Wq + (size_t)(bn * 128) * 1024 + kb * 64, 1024);
        __syncthreads();
#pragma unroll
        for (int kk = 0; kk < 2; ++kk) {
            bf16x8 af[4], bfr[4];
#pragma unroll
            for (int m = 0; m < 4; ++m) {
                int row = wr * 64 + m * 16 + lr;
                af[m] = as_bf(*(const u16x8*)(&As[row * 64 + (((kk * 4 + lg) ^ (lr & 7)) << 3)]));
            }
#pragma unroll
            for (int n = 0; n < 4; ++n) {
                int row = wc * 64 + n * 16 + lr;
                bfr[n] = as_bf(*(const u16x8*)(&Bs[row * 64 + (((kk * 4 + lg) ^ (lr & 7)) << 3)]));
            }
#pragma unroll
            for (int m = 0; m < 4; ++m)
#pragma unroll
                for (int n = 0; n < 4; ++n)
                    acc[m][n] = __builtin_amdgcn_mfma_f32_16x16x32_bf16(af[m], bfr[n], acc[m][n], 0, 0, 0);
        }
    }
    const int row0 = bm * 128 + wr * 64;
    const int col0 = bn * 128 + wc * 64;
#pragma unroll
    for (int m = 0; m < 4; ++m)
#pragma unroll
        for (int n = 0; n < 4; ++n)
#pragma unroll
            for (int r = 0; r < 4; ++r)
                Gt[(size_t)(row0 + m * 16 + lg * 4 + r) * 1024 + col0 + n * 16 + lr]
                    = f2bf(acc[m][n][r]);
}

// ---------------------------------------------------------------------------
// Kernel 3: per-batch Y/V GEMM. C[4096][2048] = X_b * [Gt | Wvt]^T.
// cols 0-1023: Y[s][j] = sum_d X[s][d] G[d][j]  -> row-major bf16.
// cols 1024-2047: V -> transposed Vt[1024 e][4096 s] bf16.
// ---------------------------------------------------------------------------
__global__ __launch_bounds__(256, 3) void yv_gemm(const float* __restrict__ X,
                                                  const u16* __restrict__ Gt,
                                                  const u16* __restrict__ Wvt,
                                                  u16* __restrict__ Y,
                                                  u16* __restrict__ Vt) {
    __shared__ u16 As[128 * 64];
    __shared__ u16 Bs[128 * 64];
    const int bid = blockIdx.x;
    const int swz = (bid & 7) * 64 + (bid >> 3);   // 512 blocks, XCD-bijective
    const int bm = swz >> 4, bn = swz & 15;
    const int tid = threadIdx.x;
    const int w = tid >> 6, l = tid & 63, lg = l >> 4, lr = l & 15;
    const int wr = w >> 1, wc = w & 1;

    const u16* bsrc = (bn < 8) ? (Gt  + (size_t)(bn * 128) * 1024)
                               : (Wvt + (size_t)((bn - 8) * 128) * 1024);

    const f32x4 z4 = {0.f, 0.f, 0.f, 0.f};
    f32x4 acc[4][4];
#pragma unroll
    for (int m = 0; m < 4; ++m)
#pragma unroll
        for (int n = 0; n < 4; ++n) acc[m][n] = z4;

    for (int kb = 0; kb < 16; ++kb) {
        __syncthreads();
        STAGE_G2L(Bs, bsrc + kb * 64, 1024, 4);
        STAGE_F2B(As, X + (size_t)(bm * 128) * 1024 + kb * 64, 1024);
        __syncthreads();
#pragma unroll
        for (int kk = 0; kk < 2; ++kk) {
            bf16x8 af[4], bfr[4];
#pragma unroll
            for (int m = 0; m < 4; ++m) {
                int row = wr * 64 + m * 16 + lr;
                af[m] = as_bf(*(const u16x8*)(&As[row * 64 + (((kk * 4 + lg) ^ (lr & 7)) << 3)]));
            }
#pragma unroll
            for (int n = 0; n < 4; ++n) {
                int row = wc * 64 + n * 16 + lr;
                bfr[n] = as_bf(*(const u16x8*)(&Bs[row * 64 + (((kk * 4 + lg) ^ (lr & 7)) << 3)]));
            }
#pragma unroll
            for (int m = 0; m < 4; ++m)
#pragma unroll
                for (int n = 0; n < 4; ++n)
                    acc[m][n] = __builtin_amdgcn_mfma_f32_16x16x32_bf16(af[m], bfr[n], acc[m][n], 0, 0, 0);
        }
    }
    const int row0 = bm * 128 + wr * 64;
    const int col0 = bn * 128 + wc * 64;
#pragma unroll
    for (int m = 0; m < 4; ++m) {
#pragma unroll
        for (int n = 0; n < 4; ++n) {
            int col = col0 + n * 16 + lr;
            int row = row0 + m * 16 + lg * 4;
            if (bn < 8) {
#pragma unroll
                for (int r = 0; r < 4; ++r) Y[(size_t)(row + r) * 1024 + col] = f2bf(acc[m][n][r]);
            } else {
                int cg = col & 1023;
                u16x4 v;
                v[0] = f2bf(acc[m][n][0]); v[1] = f2bf(acc[m][n][1]);
                v[2] = f2bf(acc[m][n][2]); v[3] = f2bf(acc[m][n][3]);
                *(u16x4*)(Vt + (size_t)cg * 4096 + row) = v;
            }
        }
    }
}

// ---------------------------------------------------------------------------
// Kernel 4: per-batch S GEMM. S = Y * X^T; P = exp2(S*KSCALE) bf16, plus
// per-row partial sums pl[row*64 + bn*2 + wc] from the SAME bf16 P values.
// A = Y (bf16, gload-staged); B = X (fp32, conv-staged).
// ---------------------------------------------------------------------------
__global__ __launch_bounds__(256, 3) void qk_gemm(const u16* __restrict__ Yb,
                                                  const float* __restrict__ Xf,
                                                  u16* __restrict__ P,
                                                  float* __restrict__ pl) {
    __shared__ u16 As[128 * 64];
    __shared__ u16 Bs[128 * 64];
    const int bid = blockIdx.x;
    const int swz = (bid & 7) * 128 + (bid >> 3);  // 1024 blocks
    const int bm = swz >> 5, bn = swz & 31;
    const int tid = threadIdx.x;
    const int w = tid >> 6, l = tid & 63, lg = l >> 4, lr = l & 15;
    const int wr = w >> 1, wc = w & 1;

    const f32x4 z4 = {0.f, 0.f, 0.f, 0.f};
    f32x4 acc[4][4];
#pragma unroll
    for (int m = 0; m < 4; ++m)
#pragma unroll
        for (int n = 0; n < 4; ++n) acc[m][n] = z4;

    for (int kb = 0; kb < 16; ++kb) {
        __syncthreads();
        STAGE_G2L(As, Yb + (size_t)(bm * 128) * 1024 + kb * 64, 1024, 4);
        STAGE_F2B(Bs, Xf + (size_t)(bn * 128) * 1024 + kb * 64, 1024);
        __syncthreads();
#pragma unroll
        for (int kk = 0; kk < 2; ++kk) {
            bf16x8 af[4], bfr[4];
#pragma unroll
            for (int m = 0; m < 4; ++m) {
                int row = wr * 64 + m * 16 + lr;
                af[m] = as_bf(*(const u16x8*)(&As[row * 64 + (((kk * 4 + lg) ^ (lr & 7)) << 3)]));
            }
#pragma unroll
            for (int n = 0; n < 4; ++n) {
                int row = wc * 64 + n * 16 + lr;
                bfr[n] = as_bf(*(const u16x8*)(&Bs[row * 64 + (((kk * 4 + lg) ^ (lr & 7)) << 3)]));
            }
#pragma unroll
            for (int m = 0; m < 4; ++m)
#pragma unroll
                for (int n = 0; n < 4; ++n)
                    acc[m][n] = __builtin_amdgcn_mfma_f32_16x16x32_bf16(af[m], bfr[n], acc[m][n], 0, 0, 0);
        }
    }
    const int row0 = bm * 128 + wr * 64;
    const int col0 = bn * 128 + wc * 64;
#pragma unroll
    for (int m = 0; m < 4; ++m) {
#pragma unroll
        for (int r = 0; r < 4; ++r) {
            const size_t rowg = (size_t)(row0 + m * 16 + lg * 4 + r);
            float se = 0.f;
#pragma unroll
            for (int n = 0; n < 4; ++n) {
                u16 pb = f2bf(exp2f(acc[m][n][r] * KSCALE));
                P[rowg * 4096 + col0 + n * 16 + lr] = pb;
                se += bf2f(pb);
            }
            se += __shfl_xor(se, 1, 64);
            se += __shfl_xor(se, 2, 64);
            se += __shfl_xor(se, 4, 64);
            se += __shfl_xor(se, 8, 64);
            if (lr == 0) pl[rowg * 64 + bn * 2 + wc] = se;
        }
    }
}

// ---------------------------------------------------------------------------
// Kernel 5: pair-fused PV GEMM. O_bb = (P_bb * V_bb) / rowsum. 128x128 tiles,
// prologue reduces 64 f32 partials per row to 1/sum.
// ---------------------------------------------------------------------------
__global__ __launch_bounds__(256, 4) void pv_pair(const u16* __restrict__ P0,
                                                  const u16* __restrict__ P1,
                                                  const u16* __restrict__ V0,
                                                  const u16* __restrict__ V1,
                                                  const float* __restrict__ pl,
                                                  float* __restrict__ Out0,
                                                  float* __restrict__ Out1) {
    __shared__ u16 As[128 * 64];
    __shared__ u16 Bs[128 * 64];
    __shared__ float rl_s[128];
    const int bid = blockIdx.x;
    const int swz = (bid & 7) * 64 + (bid >> 3);   // 512 blocks, XCD-bijective
    const int bb = swz >> 8, rem = swz & 255;
    const int bm = rem >> 3, bn = rem & 7;
    const int q0 = bm * 128, e0 = bn * 128;
    const u16* P  = bb ? P1 : P0;
    const u16* Vt = bb ? V1 : V0;
    float* Out    = bb ? Out1 : Out0;
    const int tid = threadIdx.x;
    const int w = tid >> 6, l = tid & 63, lg = l >> 4, lr = l & 15;
    const int wr = w >> 1, wc = w & 1;

    if (tid < 128) {
        const f32x4* pp = (const f32x4*)(pl + (size_t)(bb * 4096 + q0 + tid) * 64);
        f32x4 a = pp[0];
#pragma unroll
        for (int i = 1; i < 16; ++i) a += pp[i];
        rl_s[tid] = 1.0f / (a[0] + a[1] + a[2] + a[3]);
    }

    const f32x4 z4 = {0.f, 0.f, 0.f, 0.f};
    f32x4 acc[4][4];
#pragma unroll
    for (int m = 0; m < 4; ++m)
#pragma unroll
        for (int n = 0; n < 4; ++n) acc[m][n] = z4;

    for (int kb = 0; kb < 64; ++kb) {
        __syncthreads();
        STAGE_G2L(As, P + (size_t)q0 * 4096 + kb * 64, 4096, 4);
        STAGE_G2L(Bs, Vt + (size_t)e0 * 4096 + kb * 64, 4096, 4);
        __syncthreads();
#pragma unroll
        for (int kk = 0; kk < 2; ++kk) {
            bf16x8 af[4], bfr[4];
#pragma unroll
            for (int m = 0; m < 4; ++m) {
                int row = wr * 64 + m * 16 + lr;
                af[m] = as_bf(*(const u16x8*)(&As[row * 64 + (((kk * 4 + lg) ^ (lr & 7)) << 3)]));
            }
#pragma unroll
            for (int n = 0; n < 4; ++n) {
                int row = wc * 64 + n * 16 + lr;
                bfr[n] = as_bf(*(const u16x8*)(&Bs[row * 64 + (((kk * 4 + lg) ^ (lr & 7)) << 3)]));
            }
#pragma unroll
            for (int m = 0; m < 4; ++m)
#pragma unroll
                for (int n = 0; n < 4; ++n)
                    acc[m][n] = __builtin_amdgcn_mfma_f32_16x16x32_bf16(af[m], bfr[n], acc[m][n], 0, 0, 0);
        }
    }
#pragma unroll
    for (int m = 0; m < 4; ++m) {
#pragma unroll
        for (int r = 0; r < 4; ++r) {
            int rloc = wr * 64 + m * 16 + lg * 4 + r;
            float rl = rl_s[rloc];
#pragma unroll
            for (int n = 0; n < 4; ++n)
                Out[(size_t)(q0 + rloc) * 1024 + e0 + wc * 64 + n * 16 + lr] = acc[m][n][r] * rl;
        }
    }
}

// ---------------------------------------------------------------------------
extern "C" void kernel_launch(void* const* d_in, const int* in_sizes, int n_in,
                              void* d_out, int out_size, void* d_ws, size_t ws_size,
                              hipStream_t stream) {
    const float* x  = (const float*)d_in[0];
    const float* Wq = (const float*)d_in[1];
    const float* Wk = (const float*)d_in[2];
    const float* Wv = (const float*)d_in[3];
    float* out = (float*)d_out;

    char* ws = (char*)d_ws;
    u16*   Gt  = (u16*)(ws);                     //  2,097,152 B
    u16*   Wvt = (u16*)(ws + 2097152);           //  2,097,152 B
    float* plg = (float*)(ws + 4194304);         //  2,097,152 B (pl0 | pl1)
    u16*   Y   = (u16*)(ws + 6291456);           //  8,388,608 B
    u16*   V0  = (u16*)(ws + 14680064);          //  8,388,608 B
    u16*   V1  = (u16*)(ws + 23068672);          //  8,388,608 B
    u16*   P0  = (u16*)(ws + 31457280);          // 33,554,432 B
    u16*   P1  = (u16*)(ws + 65011712);          // 33,554,432 B  (total 98,566,144 < proven 106,954,752)

    wt_kernel<<<dim3(16, 16), 256, 0, stream>>>(Wv, Wvt);
    g_gemm<<<dim3(64), 256, 0, stream>>>(Wk, Wq, Gt);
    for (int p = 0; p < 2; ++p) {
        const float* x0 = x + (size_t)(2 * p) * 4194304;
        const float* x1 = x + (size_t)(2 * p + 1) * 4194304;
        float* o0 = out + (size_t)(2 * p) * 4194304;
        float* o1 = out + (size_t)(2 * p + 1) * 4194304;
        yv_gemm<<<dim3(512), 256, 0, stream>>>(x0, Gt, Wvt, Y, V0);
        qk_gemm<<<dim3(1024), 256, 0, stream>>>(Y, x0, P0, plg);
        yv_gemm<<<dim3(512), 256, 0, stream>>>(x1, Gt, Wvt, Y, V1);
        qk_gemm<<<dim3(1024), 256, 0, stream>>>(Y, x1, P1, plg + 262144);
        pv_pair<<<dim3(512), 256, 0, stream>>>(P0, P1, V0, V1, plg, o0, o1);
    }
}

// Round 12
// 513.651 us; speedup vs baseline: 1.1601x; 1.1601x over previous
//
#include <hip/hip_runtime.h>

typedef unsigned short u16;
typedef float f32x4 __attribute__((ext_vector_type(4)));
typedef u16   u16x4 __attribute__((ext_vector_type(4)));
typedef u16   u16x8 __attribute__((ext_vector_type(8)));
typedef __bf16 bf16x8 __attribute__((ext_vector_type(8)));

static __device__ __forceinline__ u16 f2bf(float x) {
    unsigned int u = __builtin_bit_cast(unsigned int, x);
    u = (u + 0x7FFFu + ((u >> 16) & 1u)) >> 16;
    return (u16)u;
}
static __device__ __forceinline__ float bf2f(u16 x) {
    unsigned int u = ((unsigned int)x) << 16;
    return __builtin_bit_cast(float, u);
}
static __device__ __forceinline__ bf16x8 as_bf(u16x8 v) { return __builtin_bit_cast(bf16x8, v); }

// async global->LDS, 16B per lane; LDS dest = wave-uniform base + lane*16
static __device__ __forceinline__ void gload16(const u16* g, u16* lds) {
    __builtin_amdgcn_global_load_lds(
        (const __attribute__((address_space(1))) void*)g,
        (__attribute__((address_space(3))) void*)lds,
        16, 0, 0);
}

#define KSCALE 0.045084220027780106f   /* log2(e)/32 */

// Stage a [128 x 64] bf16 tile into LDS via global_load_lds; read-side XOR
// swizzle baked into the per-lane GLOBAL address (linear dest + swz source).
#define STAGE_G2L(dst, src, stride, ROUNDS) do {                               \
    _Pragma("unroll") for (int i_ = 0; i_ < (ROUNDS); ++i_) {                  \
        int c_ = (i_ * 4 + w) * 64 + l;                                        \
        int row_ = c_ >> 3, c8_ = c_ & 7;                                      \
        gload16((src) + (size_t)row_ * (stride) + ((c8_ ^ (row_ & 7)) << 3),   \
                &(dst)[(i_ * 4 + w) * 512]);                                   \
    } } while (0)

// Stage a [128 x 64] tile from FP32 global, converting to bf16, with the
// swizzled LDS image (write-side swizzle; proven since round 0).
#define STAGE_F2B(dst, src, stride) do {                                       \
    _Pragma("unroll") for (int i_ = 0; i_ < 4; ++i_) {                         \
        int cid_ = i_ * 256 + tid;                                             \
        int row_ = cid_ >> 3, c8_ = cid_ & 7;                                  \
        const float* s_ = (src) + (size_t)row_ * (stride) + c8_ * 8;           \
        f32x4 v0_ = *(const f32x4*)(s_);                                       \
        f32x4 v1_ = *(const f32x4*)(s_ + 4);                                   \
        u16x8 t_;                                                              \
        t_[0] = f2bf(v0_[0]); t_[1] = f2bf(v0_[1]);                            \
        t_[2] = f2bf(v0_[2]); t_[3] = f2bf(v0_[3]);                            \
        t_[4] = f2bf(v1_[0]); t_[5] = f2bf(v1_[1]);                            \
        t_[6] = f2bf(v1_[2]); t_[7] = f2bf(v1_[3]);                            \
        *(u16x8*)(&(dst)[row_ * 64 + ((c8_ ^ (row_ & 7)) << 3)]) = t_;         \
    } } while (0)

// ---------------------------------------------------------------------------
// Kernel 1: Wv [1024 d][1024 e] fp32 -> Wvt [1024 e][1024 d] bf16 (transpose)
// ---------------------------------------------------------------------------
__global__ __launch_bounds__(256) void wt_kernel(const float* __restrict__ Wv,
                                                 u16* __restrict__ Wvt) {
    __shared__ float tile[64][65];
    const int bx = blockIdx.x, by = blockIdx.y;
    const int tid = threadIdx.x;
#pragma unroll
    for (int i = 0; i < 16; ++i) {
        int idx = i * 256 + tid;
        int r = idx >> 6, c = idx & 63;
        tile[r][c] = Wv[(by * 64 + r) * 1024 + bx * 64 + c];
    }
    __syncthreads();
#pragma unroll
    for (int i = 0; i < 16; ++i) {
        int idx = i * 256 + tid;
        int r = idx >> 6, c = idx & 63;
        Wvt[(bx * 64 + r) * 1024 + by * 64 + c] = f2bf(tile[c][r]);
    }
}

// ---------------------------------------------------------------------------
// Kernel 2: Gt[d'][d] = sum_e Wk[d'][e] * Wq[d][e]  (= (Wq*Wk^T)^T, bf16).
// ---------------------------------------------------------------------------
__global__ __launch_bounds__(256, 3) void g_gemm(const float* __restrict__ Wk,
                                                 const float* __restrict__ Wq,
                                                 u16* __restrict__ Gt) {
    __shared__ u16 As[128 * 64];
    __shared__ u16 Bs[128 * 64];
    const int bid = blockIdx.x;
    const int bm = bid >> 3, bn = bid & 7;
    const int tid = threadIdx.x;
    const int w = tid >> 6, l = tid & 63, lg = l >> 4, lr = l & 15;
    const int wr = w >> 1, wc = w & 1;

    const f32x4 z4 = {0.f, 0.f, 0.f, 0.f};
    f32x4 acc[4][4];
#pragma unroll
    for (int m = 0; m < 4; ++m)
#pragma unroll
        for (int n = 0; n < 4; ++n) acc[m][n] = z4;

    for (int kb = 0; kb < 16; ++kb) {
        __syncthreads();
        STAGE_F2B(As, Wk + (size_t)(bm * 128) * 1024 + kb * 64, 1024);
        STAGE_F2B(Bs, Wq + (size_t)(bn * 128) * 1024 + kb * 64, 1024);
        __syncthreads();
#pragma unroll
        for (int kk = 0; kk < 2; ++kk) {
            bf16x8 af[4], bfr[4];
#pragma unroll
            for (int m = 0; m < 4; ++m) {
                int row = wr * 64 + m * 16 + lr;
                af[m] = as_bf(*(const u16x8*)(&As[row * 64 + (((kk * 4 + lg) ^ (lr & 7)) << 3)]));
            }
#pragma unroll
            for (int n = 0; n < 4; ++n) {
                int row = wc * 64 + n * 16 + lr;
                bfr[n] = as_bf(*(const u16x8*)(&Bs[row * 64 + (((kk * 4 + lg) ^ (lr & 7)) << 3)]));
            }
#pragma unroll
            for (int m = 0; m < 4; ++m)
#pragma unroll
                for (int n = 0; n < 4; ++n)
                    acc[m][n] = __builtin_amdgcn_mfma_f32_16x16x32_bf16(af[m], bfr[n], acc[m][n], 0, 0, 0);
        }
    }
    const int row0 = bm * 128 + wr * 64;
    const int col0 = bn * 128 + wc * 64;
#pragma unroll
    for (int m = 0; m < 4; ++m)
#pragma unroll
        for (int n = 0; n < 4; ++n)
#pragma unroll
            for (int r = 0; r < 4; ++r)
                Gt[(size_t)(row0 + m * 16 + lg * 4 + r) * 1024 + col0 + n * 16 + lr]
                    = f2bf(acc[m][n][r]);
}

// ---------------------------------------------------------------------------
// Kernel 3: per-batch Y/V GEMM. C[4096][2048] = X_b * [Gt | Wvt]^T.
// cols 0-1023: Y row-major bf16; cols 1024-2047: V -> Vt[1024 e][4096 s].
// SIDE EFFECT: bn==0 blocks also store their converted A tiles as Xb
// (bf16 copy of X_b, row-major) for qk's gload-staged B operand.
// ---------------------------------------------------------------------------
__global__ __launch_bounds__(256, 3) void yv_gemm(const float* __restrict__ X,
                                                  const u16* __restrict__ Gt,
                                                  const u16* __restrict__ Wvt,
                                                  u16* __restrict__ Y,
                                                  u16* __restrict__ Vt,
                                                  u16* __restrict__ Xb) {
    __shared__ u16 As[128 * 64];
    __shared__ u16 Bs[128 * 64];
    const int bid = blockIdx.x;
    const int swz = (bid & 7) * 64 + (bid >> 3);   // 512 blocks, XCD-bijective
    const int bm = swz >> 4, bn = swz & 15;
    const int tid = threadIdx.x;
    const int w = tid >> 6, l = tid & 63, lg = l >> 4, lr = l & 15;
    const int wr = w >> 1, wc = w & 1;

    const u16* bsrc = (bn < 8) ? (Gt  + (size_t)(bn * 128) * 1024)
                               : (Wvt + (size_t)((bn - 8) * 128) * 1024);
    const bool write_xb = (bn == 0);

    const f32x4 z4 = {0.f, 0.f, 0.f, 0.f};
    f32x4 acc[4][4];
#pragma unroll
    for (int m = 0; m < 4; ++m)
#pragma unroll
        for (int n = 0; n < 4; ++n) acc[m][n] = z4;

    for (int kb = 0; kb < 16; ++kb) {
        __syncthreads();
        STAGE_G2L(Bs, bsrc + kb * 64, 1024, 4);
        // A: conv-stage X tile; bn==0 blocks also persist the bf16 tile to Xb
#pragma unroll
        for (int i_ = 0; i_ < 4; ++i_) {
            int cid_ = i_ * 256 + tid;
            int row_ = cid_ >> 3, c8_ = cid_ & 7;
            const float* s_ = X + (size_t)(bm * 128 + row_) * 1024 + kb * 64 + c8_ * 8;
            f32x4 v0_ = *(const f32x4*)(s_);
            f32x4 v1_ = *(const f32x4*)(s_ + 4);
            u16x8 t_;
            t_[0] = f2bf(v0_[0]); t_[1] = f2bf(v0_[1]);
            t_[2] = f2bf(v0_[2]); t_[3] = f2bf(v0_[3]);
            t_[4] = f2bf(v1_[0]); t_[5] = f2bf(v1_[1]);
            t_[6] = f2bf(v1_[2]); t_[7] = f2bf(v1_[3]);
            *(u16x8*)(&As[row_ * 64 + ((c8_ ^ (row_ & 7)) << 3)]) = t_;
            if (write_xb)
                *(u16x8*)(Xb + (size_t)(bm * 128 + row_) * 1024 + kb * 64 + c8_ * 8) = t_;
        }
        __syncthreads();
#pragma unroll
        for (int kk = 0; kk < 2; ++kk) {
            bf16x8 af[4], bfr[4];
#pragma unroll
            for (int m = 0; m < 4; ++m) {
                int row = wr * 64 + m * 16 + lr;
                af[m] = as_bf(*(const u16x8*)(&As[row * 64 + (((kk * 4 + lg) ^ (lr & 7)) << 3)]));
            }
#pragma unroll
            for (int n = 0; n < 4; ++n) {
                int row = wc * 64 + n * 16 + lr;
                bfr[n] = as_bf(*(const u16x8*)(&Bs[row * 64 + (((kk * 4 + lg) ^ (lr & 7)) << 3)]));
            }
#pragma unroll
            for (int m = 0; m < 4; ++m)
#pragma unroll
                for (int n = 0; n < 4; ++n)
                    acc[m][n] = __builtin_amdgcn_mfma_f32_16x16x32_bf16(af[m], bfr[n], acc[m][n], 0, 0, 0);
        }
    }
    const int row0 = bm * 128 + wr * 64;
    const int col0 = bn * 128 + wc * 64;
#pragma unroll
    for (int m = 0; m < 4; ++m) {
#pragma unroll
        for (int n = 0; n < 4; ++n) {
            int col = col0 + n * 16 + lr;
            int row = row0 + m * 16 + lg * 4;
            if (bn < 8) {
#pragma unroll
                for (int r = 0; r < 4; ++r) Y[(size_t)(row + r) * 1024 + col] = f2bf(acc[m][n][r]);
            } else {
                int cg = col & 1023;
                u16x4 v;
                v[0] = f2bf(acc[m][n][0]); v[1] = f2bf(acc[m][n][1]);
                v[2] = f2bf(acc[m][n][2]); v[3] = f2bf(acc[m][n][3]);
                *(u16x4*)(Vt + (size_t)cg * 4096 + row) = v;
            }
        }
    }
}

// ---------------------------------------------------------------------------
// Kernel 4: per-batch S GEMM. S = Y * Xb^T; P = exp2(S*KSCALE) bf16, plus
// per-row partial sums pl. Both operands bf16 gload-staged (round-10 proven).
// ---------------------------------------------------------------------------
__global__ __launch_bounds__(256, 4) void qk_gemm(const u16* __restrict__ Yb,
                                                  const u16* __restrict__ Xb,
                                                  u16* __restrict__ P,
                                                  float* __restrict__ pl) {
    __shared__ u16 As[128 * 64];
    __shared__ u16 Bs[128 * 64];
    const int bid = blockIdx.x;
    const int swz = (bid & 7) * 128 + (bid >> 3);  // 1024 blocks
    const int bm = swz >> 5, bn = swz & 31;
    const int tid = threadIdx.x;
    const int w = tid >> 6, l = tid & 63, lg = l >> 4, lr = l & 15;
    const int wr = w >> 1, wc = w & 1;

    const f32x4 z4 = {0.f, 0.f, 0.f, 0.f};
    f32x4 acc[4][4];
#pragma unroll
    for (int m = 0; m < 4; ++m)
#pragma unroll
        for (int n = 0; n < 4; ++n) acc[m][n] = z4;

    for (int kb = 0; kb < 16; ++kb) {
        __syncthreads();
        STAGE_G2L(As, Yb + (size_t)(bm * 128) * 1024 + kb * 64, 1024, 4);
        STAGE_G2L(Bs, Xb + (size_t)(bn * 128) * 1024 + kb * 64, 1024, 4);
        __syncthreads();
#pragma unroll
        for (int kk = 0; kk < 2; ++kk) {
            bf16x8 af[4], bfr[4];
#pragma unroll
            for (int m = 0; m < 4; ++m) {
                int row = wr * 64 + m * 16 + lr;
                af[m] = as_bf(*(const u16x8*)(&As[row * 64 + (((kk * 4 + lg) ^ (lr & 7)) << 3)]));
            }
#pragma unroll
            for (int n = 0; n < 4; ++n) {
                int row = wc * 64 + n * 16 + lr;
                bfr[n] = as_bf(*(const u16x8*)(&Bs[row * 64 + (((kk * 4 + lg) ^ (lr & 7)) << 3)]));
            }
#pragma unroll
            for (int m = 0; m < 4; ++m)
#pragma unroll
                for (int n = 0; n < 4; ++n)
                    acc[m][n] = __builtin_amdgcn_mfma_f32_16x16x32_bf16(af[m], bfr[n], acc[m][n], 0, 0, 0);
        }
    }
    const int row0 = bm * 128 + wr * 64;
    const int col0 = bn * 128 + wc * 64;
#pragma unroll
    for (int m = 0; m < 4; ++m) {
#pragma unroll
        for (int r = 0; r < 4; ++r) {
            const size_t rowg = (size_t)(row0 + m * 16 + lg * 4 + r);
            float se = 0.f;
#pragma unroll
            for (int n = 0; n < 4; ++n) {
                u16 pb = f2bf(exp2f(acc[m][n][r] * KSCALE));
                P[rowg * 4096 + col0 + n * 16 + lr] = pb;
                se += bf2f(pb);
            }
            se += __shfl_xor(se, 1, 64);
            se += __shfl_xor(se, 2, 64);
            se += __shfl_xor(se, 4, 64);
            se += __shfl_xor(se, 8, 64);
            if (lr == 0) pl[rowg * 64 + bn * 2 + wc] = se;
        }
    }
}

// ---------------------------------------------------------------------------
// Kernel 5: pair-fused PV GEMM. O_bb = (P_bb * V_bb) / rowsum.
// ---------------------------------------------------------------------------
__global__ __launch_bounds__(256, 4) void pv_pair(const u16* __restrict__ P0,
                                                  const u16* __restrict__ P1,
                                                  const u16* __restrict__ V0,
                                                  const u16* __restrict__ V1,
                                                  const float* __restrict__ pl,
                                                  float* __restrict__ Out0,
                                                  float* __restrict__ Out1) {
    __shared__ u16 As[128 * 64];
    __shared__ u16 Bs[128 * 64];
    __shared__ float rl_s[128];
    const int bid = blockIdx.x;
    const int swz = (bid & 7) * 64 + (bid >> 3);   // 512 blocks, XCD-bijective
    const int bb = swz >> 8, rem = swz & 255;
    const int bm = rem >> 3, bn = rem & 7;
    const int q0 = bm * 128, e0 = bn * 128;
    const u16* P  = bb ? P1 : P0;
    const u16* Vt = bb ? V1 : V0;
    float* Out    = bb ? Out1 : Out0;
    const int tid = threadIdx.x;
    const int w = tid >> 6, l = tid & 63, lg = l >> 4, lr = l & 15;
    const int wr = w >> 1, wc = w & 1;

    if (tid < 128) {
        const f32x4* pp = (const f32x4*)(pl + (size_t)(bb * 4096 + q0 + tid) * 64);
        f32x4 a = pp[0];
#pragma unroll
        for (int i = 1; i < 16; ++i) a += pp[i];
        rl_s[tid] = 1.0f / (a[0] + a[1] + a[2] + a[3]);
    }

    const f32x4 z4 = {0.f, 0.f, 0.f, 0.f};
    f32x4 acc[4][4];
#pragma unroll
    for (int m = 0; m < 4; ++m)
#pragma unroll
        for (int n = 0; n < 4; ++n) acc[m][n] = z4;

    for (int kb = 0; kb < 64; ++kb) {
        __syncthreads();
        STAGE_G2L(As, P + (size_t)q0 * 4096 + kb * 64, 4096, 4);
        STAGE_G2L(Bs, Vt + (size_t)e0 * 4096 + kb * 64, 4096, 4);
        __syncthreads();
#pragma unroll
        for (int kk = 0; kk < 2; ++kk) {
            bf16x8 af[4], bfr[4];
#pragma unroll
            for (int m = 0; m < 4; ++m) {
                int row = wr * 64 + m * 16 + lr;
                af[m] = as_bf(*(const u16x8*)(&As[row * 64 + (((kk * 4 + lg) ^ (lr & 7)) << 3)]));
            }
#pragma unroll
            for (int n = 0; n < 4; ++n) {
                int row = wc * 64 + n * 16 + lr;
                bfr[n] = as_bf(*(const u16x8*)(&Bs[row * 64 + (((kk * 4 + lg) ^ (lr & 7)) << 3)]));
            }
#pragma unroll
            for (int m = 0; m < 4; ++m)
#pragma unroll
                for (int n = 0; n < 4; ++n)
                    acc[m][n] = __builtin_amdgcn_mfma_f32_16x16x32_bf16(af[m], bfr[n], acc[m][n], 0, 0, 0);
        }
    }
#pragma unroll
    for (int m = 0; m < 4; ++m) {
#pragma unroll
        for (int r = 0; r < 4; ++r) {
            int rloc = wr * 64 + m * 16 + lg * 4 + r;
            float rl = rl_s[rloc];
#pragma unroll
            for (int n = 0; n < 4; ++n)
                Out[(size_t)(q0 + rloc) * 1024 + e0 + wc * 64 + n * 16 + lr] = acc[m][n][r] * rl;
        }
    }
}

// ---------------------------------------------------------------------------
extern "C" void kernel_launch(void* const* d_in, const int* in_sizes, int n_in,
                              void* d_out, int out_size, void* d_ws, size_t ws_size,
                              hipStream_t stream) {
    const float* x  = (const float*)d_in[0];
    const float* Wq = (const float*)d_in[1];
    const float* Wk = (const float*)d_in[2];
    const float* Wv = (const float*)d_in[3];
    float* out = (float*)d_out;

    char* ws = (char*)d_ws;
    u16*   Gt  = (u16*)(ws);                     //  2,097,152 B
    u16*   Wvt = (u16*)(ws + 2097152);           //  2,097,152 B
    float* plg = (float*)(ws + 4194304);         //  2,097,152 B (pl0 | pl1)
    u16*   Y   = (u16*)(ws + 6291456);           //  8,388,608 B
    u16*   Xb  = (u16*)(ws + 14680064);          //  8,388,608 B (bf16 X copy)
    u16*   V0  = (u16*)(ws + 23068672);          //  8,388,608 B
    u16*   V1  = (u16*)(ws + 31457280);          //  8,388,608 B
    u16*   P0  = (u16*)(ws + 39845888);          // 33,554,432 B
    u16*   P1  = (u16*)(ws + 73400320);          // 33,554,432 B  (total 106,954,752 = proven)

    wt_kernel<<<dim3(16, 16), 256, 0, stream>>>(Wv, Wvt);
    g_gemm<<<dim3(64), 256, 0, stream>>>(Wk, Wq, Gt);
    for (int p = 0; p < 2; ++p) {
        const float* x0 = x + (size_t)(2 * p) * 4194304;
        const float* x1 = x + (size_t)(2 * p + 1) * 4194304;
        float* o0 = out + (size_t)(2 * p) * 4194304;
        float* o1 = out + (size_t)(2 * p + 1) * 4194304;
        yv_gemm<<<dim3(512), 256, 0, stream>>>(x0, Gt, Wvt, Y, V0, Xb);
        qk_gemm<<<dim3(1024), 256, 0, stream>>>(Y, Xb, P0, plg);
        yv_gemm<<<dim3(512), 256, 0, stream>>>(x1, Gt, Wvt, Y, V1, Xb);
        qk_gemm<<<dim3(1024), 256, 0, stream>>>(Y, Xb, P1, plg + 262144);
        pv_pair<<<dim3(512), 256, 0, stream>>>(P0, P1, V0, V1, plg, o0, o1);
    }
}

// Round 13
// 479.600 us; speedup vs baseline: 1.2424x; 1.0710x over previous
//
#include <hip/hip_runtime.h>

typedef unsigned short u16;
typedef float f32x4 __attribute__((ext_vector_type(4)));
typedef u16   u16x4 __attribute__((ext_vector_type(4)));
typedef u16   u16x8 __attribute__((ext_vector_type(8)));
typedef __bf16 bf16x8 __attribute__((ext_vector_type(8)));

static __device__ __forceinline__ u16 f2bf(float x) {
    unsigned int u = __builtin_bit_cast(unsigned int, x);
    u = (u + 0x7FFFu + ((u >> 16) & 1u)) >> 16;
    return (u16)u;
}
static __device__ __forceinline__ float bf2f(u16 x) {
    unsigned int u = ((unsigned int)x) << 16;
    return __builtin_bit_cast(float, u);
}
static __device__ __forceinline__ bf16x8 as_bf(u16x8 v) { return __builtin_bit_cast(bf16x8, v); }

// async global->LDS, 16B per lane; LDS dest = wave-uniform base + lane*16
static __device__ __forceinline__ void gload16(const u16* g, u16* lds) {
    __builtin_amdgcn_global_load_lds(
        (const __attribute__((address_space(1))) void*)g,
        (__attribute__((address_space(3))) void*)lds,
        16, 0, 0);
}

#define KSCALE 0.045084220027780106f   /* log2(e)/32 */

// Stage a [128 x 64] bf16 tile into LDS via global_load_lds; read-side XOR
// swizzle baked into the per-lane GLOBAL address (linear dest + swz source).
#define STAGE_G2L(dst, src, stride, ROUNDS) do {                               \
    _Pragma("unroll") for (int i_ = 0; i_ < (ROUNDS); ++i_) {                  \
        int c_ = (i_ * 4 + w) * 64 + l;                                        \
        int row_ = c_ >> 3, c8_ = c_ & 7;                                      \
        gload16((src) + (size_t)row_ * (stride) + ((c8_ ^ (row_ & 7)) << 3),   \
                &(dst)[(i_ * 4 + w) * 512]);                                   \
    } } while (0)

// Stage a [128 x 128] bf16 tile (BK=128): 16 8-elem chunks per row, same
// XOR involution on the low 3 bits of the chunk index.
#define STAGE_G2L128(dst, src, stride) do {                                    \
    _Pragma("unroll") for (int i_ = 0; i_ < 8; ++i_) {                         \
        int c_ = (i_ * 4 + w) * 64 + l;                                        \
        int row_ = c_ >> 4, c16_ = c_ & 15;                                    \
        gload16((src) + (size_t)row_ * (stride) + ((c16_ ^ (row_ & 7)) << 3),  \
                &(dst)[(i_ * 4 + w) * 512]);                                   \
    } } while (0)

// Stage a [ROWSx64] tile from FP32 global, converting to bf16 (write-swizzle).
#define STAGE_F2B(dst, src, stride, ITERS) do {                                \
    _Pragma("unroll") for (int i_ = 0; i_ < (ITERS); ++i_) {                   \
        int cid_ = i_ * 256 + tid;                                             \
        int row_ = cid_ >> 3, c8_ = cid_ & 7;                                  \
        const float* s_ = (src) + (size_t)row_ * (stride) + c8_ * 8;           \
        f32x4 v0_ = *(const f32x4*)(s_);                                       \
        f32x4 v1_ = *(const f32x4*)(s_ + 4);                                   \
        u16x8 t_;                                                              \
        t_[0] = f2bf(v0_[0]); t_[1] = f2bf(v0_[1]);                            \
        t_[2] = f2bf(v0_[2]); t_[3] = f2bf(v0_[3]);                            \
        t_[4] = f2bf(v1_[0]); t_[5] = f2bf(v1_[1]);                            \
        t_[6] = f2bf(v1_[2]); t_[7] = f2bf(v1_[3]);                            \
        *(u16x8*)(&(dst)[row_ * 64 + ((c8_ ^ (row_ & 7)) << 3)]) = t_;         \
    } } while (0)

// ---------------------------------------------------------------------------
// Kernel 1: Wv [1024 d][1024 e] fp32 -> Wvt [1024 e][1024 d] bf16 (transpose)
// ---------------------------------------------------------------------------
__global__ __launch_bounds__(256) void wt_kernel(const float* __restrict__ Wv,
                                                 u16* __restrict__ Wvt) {
    __shared__ float tile[64][65];
    const int bx = blockIdx.x, by = blockIdx.y;
    const int tid = threadIdx.x;
#pragma unroll
    for (int i = 0; i < 16; ++i) {
        int idx = i * 256 + tid;
        int r = idx >> 6, c = idx & 63;
        tile[r][c] = Wv[(by * 64 + r) * 1024 + bx * 64 + c];
    }
    __syncthreads();
#pragma unroll
    for (int i = 0; i < 16; ++i) {
        int idx = i * 256 + tid;
        int r = idx >> 6, c = idx & 63;
        Wvt[(bx * 64 + r) * 1024 + by * 64 + c] = f2bf(tile[c][r]);
    }
}

// ---------------------------------------------------------------------------
// Kernel 2: Gt[d'][d] = sum_e Wk[d'][e] * Wq[d][e]  (= (Wq*Wk^T)^T, bf16).
// 64x64 tiles -> 256 blocks (4x the memory-level parallelism of round 12's
// 64-block version; this kernel is latency-bound on fp32 weight reads).
// ---------------------------------------------------------------------------
__global__ __launch_bounds__(256, 3) void g_gemm(const float* __restrict__ Wk,
                                                 const float* __restrict__ Wq,
                                                 u16* __restrict__ Gt) {
    __shared__ u16 As[64 * 64];
    __shared__ u16 Bs[64 * 64];
    const int bid = blockIdx.x;
    const int swz = (bid & 7) * 32 + (bid >> 3);   // 256 blocks, XCD-bijective
    const int bm = swz >> 4, bn = swz & 15;
    const int tid = threadIdx.x;
    const int w = tid >> 6, l = tid & 63, lg = l >> 4, lr = l & 15;
    const int wr = w >> 1, wc = w & 1;

    const f32x4 z4 = {0.f, 0.f, 0.f, 0.f};
    f32x4 acc[2][2];
#pragma unroll
    for (int m = 0; m < 2; ++m)
#pragma unroll
        for (int n = 0; n < 2; ++n) acc[m][n] = z4;

    for (int kb = 0; kb < 16; ++kb) {
        __syncthreads();
        STAGE_F2B(As, Wk + (size_t)(bm * 64) * 1024 + kb * 64, 1024, 2);
        STAGE_F2B(Bs, Wq + (size_t)(bn * 64) * 1024 + kb * 64, 1024, 2);
        __syncthreads();
#pragma unroll
        for (int kk = 0; kk < 2; ++kk) {
            bf16x8 af[2], bfr[2];
#pragma unroll
            for (int m = 0; m < 2; ++m) {
                int row = wr * 32 + m * 16 + lr;
                af[m] = as_bf(*(const u16x8*)(&As[row * 64 + (((kk * 4 + lg) ^ (row & 7)) << 3)]));
            }
#pragma unroll
            for (int n = 0; n < 2; ++n) {
                int row = wc * 32 + n * 16 + lr;
                bfr[n] = as_bf(*(const u16x8*)(&Bs[row * 64 + (((kk * 4 + lg) ^ (row & 7)) << 3)]));
            }
#pragma unroll
            for (int m = 0; m < 2; ++m)
#pragma unroll
                for (int n = 0; n < 2; ++n)
                    acc[m][n] = __builtin_amdgcn_mfma_f32_16x16x32_bf16(af[m], bfr[n], acc[m][n], 0, 0, 0);
        }
    }
    const int row0 = bm * 64 + wr * 32;
    const int col0 = bn * 64 + wc * 32;
#pragma unroll
    for (int m = 0; m < 2; ++m)
#pragma unroll
        for (int n = 0; n < 2; ++n)
#pragma unroll
            for (int r = 0; r < 4; ++r)
                Gt[(size_t)(row0 + m * 16 + lg * 4 + r) * 1024 + col0 + n * 16 + lr]
                    = f2bf(acc[m][n][r]);
}

// ---------------------------------------------------------------------------
// Kernel 3: per-batch Y/V GEMM. C[4096][2048] = X_b * [Gt | Wvt]^T.
// cols 0-1023: Y row-major bf16; cols 1024-2047: V -> Vt[1024 e][4096 s].
// bn==0 blocks also persist their converted A tiles as Xb (bf16 X copy).
// ---------------------------------------------------------------------------
__global__ __launch_bounds__(256, 3) void yv_gemm(const float* __restrict__ X,
                                                  const u16* __restrict__ Gt,
                                                  const u16* __restrict__ Wvt,
                                                  u16* __restrict__ Y,
                                                  u16* __restrict__ Vt,
                                                  u16* __restrict__ Xb) {
    __shared__ u16 As[128 * 64];
    __shared__ u16 Bs[128 * 64];
    const int bid = blockIdx.x;
    const int swz = (bid & 7) * 64 + (bid >> 3);   // 512 blocks, XCD-bijective
    const int bm = swz >> 4, bn = swz & 15;
    const int tid = threadIdx.x;
    const int w = tid >> 6, l = tid & 63, lg = l >> 4, lr = l & 15;
    const int wr = w >> 1, wc = w & 1;

    const u16* bsrc = (bn < 8) ? (Gt  + (size_t)(bn * 128) * 1024)
                               : (Wvt + (size_t)((bn - 8) * 128) * 1024);
    const bool write_xb = (bn == 0);

    const f32x4 z4 = {0.f, 0.f, 0.f, 0.f};
    f32x4 acc[4][4];
#pragma unroll
    for (int m = 0; m < 4; ++m)
#pragma unroll
        for (int n = 0; n < 4; ++n) acc[m][n] = z4;

    for (int kb = 0; kb < 16; ++kb) {
        __syncthreads();
        STAGE_G2L(Bs, bsrc + kb * 64, 1024, 4);
#pragma unroll
        for (int i_ = 0; i_ < 4; ++i_) {
            int cid_ = i_ * 256 + tid;
            int row_ = cid_ >> 3, c8_ = cid_ & 7;
            const float* s_ = X + (size_t)(bm * 128 + row_) * 1024 + kb * 64 + c8_ * 8;
            f32x4 v0_ = *(const f32x4*)(s_);
            f32x4 v1_ = *(const f32x4*)(s_ + 4);
            u16x8 t_;
            t_[0] = f2bf(v0_[0]); t_[1] = f2bf(v0_[1]);
            t_[2] = f2bf(v0_[2]); t_[3] = f2bf(v0_[3]);
            t_[4] = f2bf(v1_[0]); t_[5] = f2bf(v1_[1]);
            t_[6] = f2bf(v1_[2]); t_[7] = f2bf(v1_[3]);
            *(u16x8*)(&As[row_ * 64 + ((c8_ ^ (row_ & 7)) << 3)]) = t_;
            if (write_xb)
                *(u16x8*)(Xb + (size_t)(bm * 128 + row_) * 1024 + kb * 64 + c8_ * 8) = t_;
        }
        __syncthreads();
#pragma unroll
        for (int kk = 0; kk < 2; ++kk) {
            bf16x8 af[4], bfr[4];
#pragma unroll
            for (int m = 0; m < 4; ++m) {
                int row = wr * 64 + m * 16 + lr;
                af[m] = as_bf(*(const u16x8*)(&As[row * 64 + (((kk * 4 + lg) ^ (lr & 7)) << 3)]));
            }
#pragma unroll
            for (int n = 0; n < 4; ++n) {
                int row = wc * 64 + n * 16 + lr;
                bfr[n] = as_bf(*(const u16x8*)(&Bs[row * 64 + (((kk * 4 + lg) ^ (lr & 7)) << 3)]));
            }
#pragma unroll
            for (int m = 0; m < 4; ++m)
#pragma unroll
                for (int n = 0; n < 4; ++n)
                    acc[m][n] = __builtin_amdgcn_mfma_f32_16x16x32_bf16(af[m], bfr[n], acc[m][n], 0, 0, 0);
        }
    }
    const int row0 = bm * 128 + wr * 64;
    const int col0 = bn * 128 + wc * 64;
#pragma unroll
    for (int m = 0; m < 4; ++m) {
#pragma unroll
        for (int n = 0; n < 4; ++n) {
            int col = col0 + n * 16 + lr;
            int row = row0 + m * 16 + lg * 4;
            if (bn < 8) {
#pragma unroll
                for (int r = 0; r < 4; ++r) Y[(size_t)(row + r) * 1024 + col] = f2bf(acc[m][n][r]);
            } else {
                int cg = col & 1023;
                u16x4 v;
                v[0] = f2bf(acc[m][n][0]); v[1] = f2bf(acc[m][n][1]);
                v[2] = f2bf(acc[m][n][2]); v[3] = f2bf(acc[m][n][3]);
                *(u16x4*)(Vt + (size_t)cg * 4096 + row) = v;
            }
        }
    }
}

// ---------------------------------------------------------------------------
// Kernel 4: per-batch S GEMM. S = Y * Xb^T; P = exp2(S*KSCALE) bf16, plus
// per-row partial sums pl. Both operands bf16 gload-staged (proven 37.5 us).
// ---------------------------------------------------------------------------
__global__ __launch_bounds__(256, 4) void qk_gemm(const u16* __restrict__ Yb,
                                                  const u16* __restrict__ Xb,
                                                  u16* __restrict__ P,
                                                  float* __restrict__ pl) {
    __shared__ u16 As[128 * 64];
    __shared__ u16 Bs[128 * 64];
    const int bid = blockIdx.x;
    const int swz = (bid & 7) * 128 + (bid >> 3);  // 1024 blocks
    const int bm = swz >> 5, bn = swz & 31;
    const int tid = threadIdx.x;
    const int w = tid >> 6, l = tid & 63, lg = l >> 4, lr = l & 15;
    const int wr = w >> 1, wc = w & 1;

    const f32x4 z4 = {0.f, 0.f, 0.f, 0.f};
    f32x4 acc[4][4];
#pragma unroll
    for (int m = 0; m < 4; ++m)
#pragma unroll
        for (int n = 0; n < 4; ++n) acc[m][n] = z4;

    for (int kb = 0; kb < 16; ++kb) {
        __syncthreads();
        STAGE_G2L(As, Yb + (size_t)(bm * 128) * 1024 + kb * 64, 1024, 4);
        STAGE_G2L(Bs, Xb + (size_t)(bn * 128) * 1024 + kb * 64, 1024, 4);
        __syncthreads();
#pragma unroll
        for (int kk = 0; kk < 2; ++kk) {
            bf16x8 af[4], bfr[4];
#pragma unroll
            for (int m = 0; m < 4; ++m) {
                int row = wr * 64 + m * 16 + lr;
                af[m] = as_bf(*(const u16x8*)(&As[row * 64 + (((kk * 4 + lg) ^ (lr & 7)) << 3)]));
            }
#pragma unroll
            for (int n = 0; n < 4; ++n) {
                int row = wc * 64 + n * 16 + lr;
                bfr[n] = as_bf(*(const u16x8*)(&Bs[row * 64 + (((kk * 4 + lg) ^ (lr & 7)) << 3)]));
            }
#pragma unroll
            for (int m = 0; m < 4; ++m)
#pragma unroll
                for (int n = 0; n < 4; ++n)
                    acc[m][n] = __builtin_amdgcn_mfma_f32_16x16x32_bf16(af[m], bfr[n], acc[m][n], 0, 0, 0);
        }
    }
    const int row0 = bm * 128 + wr * 64;
    const int col0 = bn * 128 + wc * 64;
#pragma unroll
    for (int m = 0; m < 4; ++m) {
#pragma unroll
        for (int r = 0; r < 4; ++r) {
            const size_t rowg = (size_t)(row0 + m * 16 + lg * 4 + r);
            float se = 0.f;
#pragma unroll
            for (int n = 0; n < 4; ++n) {
                u16 pb = f2bf(exp2f(acc[m][n][r] * KSCALE));
                P[rowg * 4096 + col0 + n * 16 + lr] = pb;
                se += bf2f(pb);
            }
            se += __shfl_xor(se, 1, 64);
            se += __shfl_xor(se, 2, 64);
            se += __shfl_xor(se, 4, 64);
            se += __shfl_xor(se, 8, 64);
            if (lr == 0) pl[rowg * 64 + bn * 2 + wc] = se;
        }
    }
}

// ---------------------------------------------------------------------------
// Kernel 5: pair-fused PV GEMM, BK=128. O_bb = (P_bb * V_bb) / rowsum.
// pv is grid-limited to 2 blocks/CU, so doubling BK costs no occupancy and
// halves barriers per MFMA (64 MFMA per barrier-pair). LDS 64.5 KB.
// ---------------------------------------------------------------------------
__global__ __launch_bounds__(256, 2) void pv_pair(const u16* __restrict__ P0,
                                                  const u16* __restrict__ P1,
                                                  const u16* __restrict__ V0,
                                                  const u16* __restrict__ V1,
                                                  const float* __restrict__ pl,
                                                  float* __restrict__ Out0,
                                                  float* __restrict__ Out1) {
    __shared__ u16 As[128 * 128];
    __shared__ u16 Bs[128 * 128];
    __shared__ float rl_s[128];
    const int bid = blockIdx.x;
    const int swz = (bid & 7) * 64 + (bid >> 3);   // 512 blocks, XCD-bijective
    const int bb = swz >> 8, rem = swz & 255;
    const int bm = rem >> 3, bn = rem & 7;
    const int q0 = bm * 128, e0 = bn * 128;
    const u16* P  = bb ? P1 : P0;
    const u16* Vt = bb ? V1 : V0;
    float* Out    = bb ? Out1 : Out0;
    const int tid = threadIdx.x;
    const int w = tid >> 6, l = tid & 63, lg = l >> 4, lr = l & 15;
    const int wr = w >> 1, wc = w & 1;

    if (tid < 128) {
        const f32x4* pp = (const f32x4*)(pl + (size_t)(bb * 4096 + q0 + tid) * 64);
        f32x4 a = pp[0];
#pragma unroll
        for (int i = 1; i < 16; ++i) a += pp[i];
        rl_s[tid] = 1.0f / (a[0] + a[1] + a[2] + a[3]);
    }

    const f32x4 z4 = {0.f, 0.f, 0.f, 0.f};
    f32x4 acc[4][4];
#pragma unroll
    for (int m = 0; m < 4; ++m)
#pragma unroll
        for (int n = 0; n < 4; ++n) acc[m][n] = z4;

    for (int kb = 0; kb < 32; ++kb) {
        __syncthreads();
        STAGE_G2L128(As, P + (size_t)q0 * 4096 + kb * 128, 4096);
        STAGE_G2L128(Bs, Vt + (size_t)e0 * 4096 + kb * 128, 4096);
        __syncthreads();
#pragma unroll
        for (int kk = 0; kk < 4; ++kk) {
            bf16x8 af[4], bfr[4];
#pragma unroll
            for (int m = 0; m < 4; ++m) {
                int row = wr * 64 + m * 16 + lr;
                af[m] = as_bf(*(const u16x8*)(&As[row * 128 + (((kk * 4 + lg) ^ (row & 7)) << 3)]));
            }
#pragma unroll
            for (int n = 0; n < 4; ++n) {
                int row = wc * 64 + n * 16 + lr;
                bfr[n] = as_bf(*(const u16x8*)(&Bs[row * 128 + (((kk * 4 + lg) ^ (row & 7)) << 3)]));
            }
#pragma unroll
            for (int m = 0; m < 4; ++m)
#pragma unroll
                for (int n = 0; n < 4; ++n)
                    acc[m][n] = __builtin_amdgcn_mfma_f32_16x16x32_bf16(af[m], bfr[n], acc[m][n], 0, 0, 0);
        }
    }
#pragma unroll
    for (int m = 0; m < 4; ++m) {
#pragma unroll
        for (int r = 0; r < 4; ++r) {
            int rloc = wr * 64 + m * 16 + lg * 4 + r;
            float rl = rl_s[rloc];
#pragma unroll
            for (int n = 0; n < 4; ++n)
                Out[(size_t)(q0 + rloc) * 1024 + e0 + wc * 64 + n * 16 + lr] = acc[m][n][r] * rl;
        }
    }
}

// ---------------------------------------------------------------------------
extern "C" void kernel_launch(void* const* d_in, const int* in_sizes, int n_in,
                              void* d_out, int out_size, void* d_ws, size_t ws_size,
                              hipStream_t stream) {
    const float* x  = (const float*)d_in[0];
    const float* Wq = (const float*)d_in[1];
    const float* Wk = (const float*)d_in[2];
    const float* Wv = (const float*)d_in[3];
    float* out = (float*)d_out;

    char* ws = (char*)d_ws;
    u16*   Gt  = (u16*)(ws);                     //  2,097,152 B
    u16*   Wvt = (u16*)(ws + 2097152);           //  2,097,152 B
    float* plg = (float*)(ws + 4194304);         //  2,097,152 B (pl0 | pl1)
    u16*   Y   = (u16*)(ws + 6291456);           //  8,388,608 B
    u16*   Xb  = (u16*)(ws + 14680064);          //  8,388,608 B (bf16 X copy)
    u16*   V0  = (u16*)(ws + 23068672);          //  8,388,608 B
    u16*   V1  = (u16*)(ws + 31457280);          //  8,388,608 B
    u16*   P0  = (u16*)(ws + 39845888);          // 33,554,432 B
    u16*   P1  = (u16*)(ws + 73400320);          // 33,554,432 B  (total 106,954,752 = proven)

    wt_kernel<<<dim3(16, 16), 256, 0, stream>>>(Wv, Wvt);
    g_gemm<<<dim3(256), 256, 0, stream>>>(Wk, Wq, Gt);
    for (int p = 0; p < 2; ++p) {
        const float* x0 = x + (size_t)(2 * p) * 4194304;
        const float* x1 = x + (size_t)(2 * p + 1) * 4194304;
        float* o0 = out + (size_t)(2 * p) * 4194304;
        float* o1 = out + (size_t)(2 * p + 1) * 4194304;
        yv_gemm<<<dim3(512), 256, 0, stream>>>(x0, Gt, Wvt, Y, V0, Xb);
        qk_gemm<<<dim3(1024), 256, 0, stream>>>(Y, Xb, P0, plg);
        yv_gemm<<<dim3(512), 256, 0, stream>>>(x1, Gt, Wvt, Y, V1, Xb);
        qk_gemm<<<dim3(1024), 256, 0, stream>>>(Y, Xb, P1, plg + 262144);
        pv_pair<<<dim3(512), 256, 0, stream>>>(P0, P1, V0, V1, plg, o0, o1);
    }
}

// Round 14
// 461.956 us; speedup vs baseline: 1.2899x; 1.0382x over previous
//
#include <hip/hip_runtime.h>

typedef unsigned short u16;
typedef float f32x4 __attribute__((ext_vector_type(4)));
typedef u16   u16x4 __attribute__((ext_vector_type(4)));
typedef u16   u16x8 __attribute__((ext_vector_type(8)));
typedef __bf16 bf16x8 __attribute__((ext_vector_type(8)));

static __device__ __forceinline__ u16 f2bf(float x) {
    unsigned int u = __builtin_bit_cast(unsigned int, x);
    u = (u + 0x7FFFu + ((u >> 16) & 1u)) >> 16;
    return (u16)u;
}
static __device__ __forceinline__ float bf2f(u16 x) {
    unsigned int u = ((unsigned int)x) << 16;
    return __builtin_bit_cast(float, u);
}
static __device__ __forceinline__ bf16x8 as_bf(u16x8 v) { return __builtin_bit_cast(bf16x8, v); }

// async global->LDS, 16B per lane; LDS dest = wave-uniform base + lane*16
static __device__ __forceinline__ void gload16(const u16* g, u16* lds) {
    __builtin_amdgcn_global_load_lds(
        (const __attribute__((address_space(1))) void*)g,
        (__attribute__((address_space(3))) void*)lds,
        16, 0, 0);
}

#define KSCALE 0.045084220027780106f   /* log2(e)/32 */

// Stage a [128 x 64] u16 tile into LDS; read-side XOR swizzle baked into the
// per-lane GLOBAL address (LDS image = linear dest, swizzled source).
// PROVEN zero-conflict with the matching read pattern (rounds 5-12).
#define STAGE_G2L(dst, src, stride, ROUNDS) do {                               \
    _Pragma("unroll") for (int i_ = 0; i_ < (ROUNDS); ++i_) {                  \
        int c_ = (i_ * 4 + w) * 64 + l;                                        \
        int row_ = c_ >> 3, c8_ = c_ & 7;                                      \
        gload16((src) + (size_t)row_ * (stride) + ((c8_ ^ (row_ & 7)) << 3),   \
                &(dst)[(i_ * 4 + w) * 512]);                                   \
    } } while (0)

// ---------------------------------------------------------------------------
// Kernel 1: W [1024 d_in][1024 d_out] fp32  ->  Wt [mat][1024 d_out][1024 d_in] bf16
// ---------------------------------------------------------------------------
__global__ __launch_bounds__(256) void wt_kernel(const float* __restrict__ Wq,
                                                 const float* __restrict__ Wk,
                                                 const float* __restrict__ Wv,
                                                 u16* __restrict__ Wt) {
    __shared__ float tile[64][65];
    const int mat = blockIdx.z;
    const float* W = (mat == 0) ? Wq : ((mat == 1) ? Wk : Wv);
    const int bx = blockIdx.x, by = blockIdx.y;
    const int tid = threadIdx.x;
#pragma unroll
    for (int i = 0; i < 16; ++i) {
        int idx = i * 256 + tid;
        int r = idx >> 6, c = idx & 63;
        tile[r][c] = W[(by * 64 + r) * 1024 + bx * 64 + c];
    }
    __syncthreads();
#pragma unroll
    for (int i = 0; i < 16; ++i) {
        int idx = i * 256 + tid;
        int r = idx >> 6, c = idx & 63;
        Wt[mat * 1048576 + (bx * 64 + r) * 1024 + by * 64 + c] = f2bf(tile[c][r]);
    }
}

// ---------------------------------------------------------------------------
// Kernel 2: per-batch QKV GEMM. C[4096][3072] = X_b * Wt^T. (round-10 proven)
// Q,K row-major bf16 [4096][1024]; V transposed: Vt[1024 e][4096 k] bf16.
// ---------------------------------------------------------------------------
__global__ __launch_bounds__(256, 3) void qkv_gemm(const float* __restrict__ X,
                                                   const u16* __restrict__ Wt,
                                                   u16* __restrict__ Qo,
                                                   u16* __restrict__ Ko,
                                                   u16* __restrict__ Vt) {
    __shared__ u16 As[128 * 64];
    __shared__ u16 Bs[128 * 64];
    const int bid = blockIdx.x;
    const int swz = (bid & 7) * 96 + (bid >> 3);   // 768 blocks, XCD-bijective
    const int bm = swz / 24, bn = swz % 24;
    const int tid = threadIdx.x;
    const int w = tid >> 6, l = tid & 63, lg = l >> 4, lr = l & 15;
    const int wr = w >> 1, wc = w & 1;

    const f32x4 z4 = {0.f, 0.f, 0.f, 0.f};
    f32x4 acc[4][4];
#pragma unroll
    for (int m = 0; m < 4; ++m)
#pragma unroll
        for (int n = 0; n < 4; ++n) acc[m][n] = z4;

    for (int kb = 0; kb < 16; ++kb) {
        __syncthreads();
        STAGE_G2L(Bs, Wt + (size_t)(bn * 128) * 1024 + kb * 64, 1024, 4);
#pragma unroll
        for (int i = 0; i < 4; ++i) {
            int cid = i * 256 + tid;
            int row = cid >> 3, c8 = cid & 7;
            const float* src = X + (bm * 128 + row) * 1024 + kb * 64 + c8 * 8;
            f32x4 v0 = *(const f32x4*)(src);
            f32x4 v1 = *(const f32x4*)(src + 4);
            u16x8 t;
            t[0] = f2bf(v0[0]); t[1] = f2bf(v0[1]); t[2] = f2bf(v0[2]); t[3] = f2bf(v0[3]);
            t[4] = f2bf(v1[0]); t[5] = f2bf(v1[1]); t[6] = f2bf(v1[2]); t[7] = f2bf(v1[3]);
            *(u16x8*)(&As[row * 64 + ((c8 ^ (row & 7)) << 3)]) = t;
        }
        __syncthreads();
#pragma unroll
        for (int kk = 0; kk < 2; ++kk) {
            bf16x8 af[4], bfr[4];
#pragma unroll
            for (int m = 0; m < 4; ++m) {
                int row = wr * 64 + m * 16 + lr;
                af[m] = as_bf(*(const u16x8*)(&As[row * 64 + (((kk * 4 + lg) ^ (lr & 7)) << 3)]));
            }
#pragma unroll
            for (int n = 0; n < 4; ++n) {
                int row = wc * 64 + n * 16 + lr;
                bfr[n] = as_bf(*(const u16x8*)(&Bs[row * 64 + (((kk * 4 + lg) ^ (lr & 7)) << 3)]));
            }
#pragma unroll
            for (int m = 0; m < 4; ++m)
#pragma unroll
                for (int n = 0; n < 4; ++n)
                    acc[m][n] = __builtin_amdgcn_mfma_f32_16x16x32_bf16(af[m], bfr[n], acc[m][n], 0, 0, 0);
        }
    }
    const int row0 = bm * 128 + wr * 64;
    const int col0 = bn * 128 + wc * 64;
#pragma unroll
    for (int m = 0; m < 4; ++m) {
#pragma unroll
        for (int n = 0; n < 4; ++n) {
            int col = col0 + n * 16 + lr;
            int mat = col >> 10;
            int cg = col & 1023;
            int row = row0 + m * 16 + lg * 4;
            if (mat == 2) {
                u16x4 v;
                v[0] = f2bf(acc[m][n][0]); v[1] = f2bf(acc[m][n][1]);
                v[2] = f2bf(acc[m][n][2]); v[3] = f2bf(acc[m][n][3]);
                *(u16x4*)(Vt + cg * 4096 + row) = v;
            } else {
                u16* P = mat ? Ko : Qo;
#pragma unroll
                for (int r = 0; r < 4; ++r) P[(row + r) * 1024 + cg] = f2bf(acc[m][n][r]);
            }
        }
    }
}

// ---------------------------------------------------------------------------
// Kernel 3: per-batch QK^T GEMM -> P[4096 q][4096 k] bf16 = exp2(QK^T * c),
// plus per-row partial sums pl[row*64 + bn*2 + wc]. (round-10 proven, 37.5us)
// ---------------------------------------------------------------------------
__global__ __launch_bounds__(256, 4) void qk_gemm(const u16* __restrict__ Qb,
                                                  const u16* __restrict__ Kb,
                                                  u16* __restrict__ P,
                                                  float* __restrict__ pl) {
    __shared__ u16 As[128 * 64];
    __shared__ u16 Bs[128 * 64];
    const int bid = blockIdx.x;
    const int swz = (bid & 7) * 128 + (bid >> 3);  // 1024 blocks
    const int bm = swz >> 5, bn = swz & 31;
    const int tid = threadIdx.x;
    const int w = tid >> 6, l = tid & 63, lg = l >> 4, lr = l & 15;
    const int wr = w >> 1, wc = w & 1;

    const f32x4 z4 = {0.f, 0.f, 0.f, 0.f};
    f32x4 acc[4][4];
#pragma unroll
    for (int m = 0; m < 4; ++m)
#pragma unroll
        for (int n = 0; n < 4; ++n) acc[m][n] = z4;

    for (int kb = 0; kb < 16; ++kb) {
        __syncthreads();
        STAGE_G2L(As, Qb + (size_t)(bm * 128) * 1024 + kb * 64, 1024, 4);
        STAGE_G2L(Bs, Kb + (size_t)(bn * 128) * 1024 + kb * 64, 1024, 4);
        __syncthreads();
#pragma unroll
        for (int kk = 0; kk < 2; ++kk) {
            bf16x8 af[4], bfr[4];
#pragma unroll
            for (int m = 0; m < 4; ++m) {
                int row = wr * 64 + m * 16 + lr;
                af[m] = as_bf(*(const u16x8*)(&As[row * 64 + (((kk * 4 + lg) ^ (lr & 7)) << 3)]));
            }
#pragma unroll
            for (int n = 0; n < 4; ++n) {
                int row = wc * 64 + n * 16 + lr;
                bfr[n] = as_bf(*(const u16x8*)(&Bs[row * 64 + (((kk * 4 + lg) ^ (lr & 7)) << 3)]));
            }
#pragma unroll
            for (int m = 0; m < 4; ++m)
#pragma unroll
                for (int n = 0; n < 4; ++n)
                    acc[m][n] = __builtin_amdgcn_mfma_f32_16x16x32_bf16(af[m], bfr[n], acc[m][n], 0, 0, 0);
        }
    }
    const int row0 = bm * 128 + wr * 64;
    const int col0 = bn * 128 + wc * 64;
#pragma unroll
    for (int m = 0; m < 4; ++m) {
#pragma unroll
        for (int r = 0; r < 4; ++r) {
            const size_t rowg = (size_t)(row0 + m * 16 + lg * 4 + r);
            float se = 0.f;
#pragma unroll
            for (int n = 0; n < 4; ++n) {
                u16 pb = f2bf(exp2f(acc[m][n][r] * KSCALE));
                P[rowg * 4096 + col0 + n * 16 + lr] = pb;
                se += bf2f(pb);
            }
            se += __shfl_xor(se, 1, 64);
            se += __shfl_xor(se, 2, 64);
            se += __shfl_xor(se, 4, 64);
            se += __shfl_xor(se, 8, 64);
            if (lr == 0) pl[rowg * 64 + bn * 2 + wc] = se;
        }
    }
}

// ---------------------------------------------------------------------------
// Kernel 4: pair-fused PV GEMM, BK=128 via SPLIT ARRAYS.
// O_bb = (P_bb * V_bb) / rowsum. Four 128x64 LDS arrays (k-chunks 0-7 / 8-15
// of the 128-wide K-slice), each staged AND read with the verbatim proven
// zero-conflict BK=64 pattern; one barrier pair per 128 K (64 MFMA).
// LDS 64.5 KB -> 2 blocks/CU (= grid limit, no occupancy loss).
// ---------------------------------------------------------------------------
__global__ __launch_bounds__(256, 2) void pv_pair(const u16* __restrict__ P0,
                                                  const u16* __restrict__ P1,
                                                  const u16* __restrict__ V0,
                                                  const u16* __restrict__ V1,
                                                  const float* __restrict__ pl,
                                                  float* __restrict__ Out0,
                                                  float* __restrict__ Out1) {
    __shared__ u16 As0[128 * 64];
    __shared__ u16 As1[128 * 64];
    __shared__ u16 Bs0[128 * 64];
    __shared__ u16 Bs1[128 * 64];
    __shared__ float rl_s[128];
    const int bid = blockIdx.x;
    const int swz = (bid & 7) * 64 + (bid >> 3);   // 512 blocks, XCD-bijective
    const int bb = swz >> 8, rem = swz & 255;
    const int bm = rem >> 3, bn = rem & 7;
    const int q0 = bm * 128, e0 = bn * 128;
    const u16* P  = bb ? P1 : P0;
    const u16* Vt = bb ? V1 : V0;
    float* Out    = bb ? Out1 : Out0;
    const int tid = threadIdx.x;
    const int w = tid >> 6, l = tid & 63, lg = l >> 4, lr = l & 15;
    const int wr = w >> 1, wc = w & 1;

    if (tid < 128) {
        const f32x4* pp = (const f32x4*)(pl + (size_t)(bb * 4096 + q0 + tid) * 64);
        f32x4 a = pp[0];
#pragma unroll
        for (int i = 1; i < 16; ++i) a += pp[i];
        rl_s[tid] = 1.0f / (a[0] + a[1] + a[2] + a[3]);
    }

    const f32x4 z4 = {0.f, 0.f, 0.f, 0.f};
    f32x4 acc[4][4];
#pragma unroll
    for (int m = 0; m < 4; ++m)
#pragma unroll
        for (int n = 0; n < 4; ++n) acc[m][n] = z4;

    for (int kb = 0; kb < 32; ++kb) {
        __syncthreads();
        STAGE_G2L(As0, P  + (size_t)q0 * 4096 + kb * 128,      4096, 4);
        STAGE_G2L(As1, P  + (size_t)q0 * 4096 + kb * 128 + 64, 4096, 4);
        STAGE_G2L(Bs0, Vt + (size_t)e0 * 4096 + kb * 128,      4096, 4);
        STAGE_G2L(Bs1, Vt + (size_t)e0 * 4096 + kb * 128 + 64, 4096, 4);
        __syncthreads();
#pragma unroll
        for (int g = 0; g < 4; ++g) {
            const u16* Aa = (g < 2) ? As0 : As1;
            const u16* Ba = (g < 2) ? Bs0 : Bs1;
            const int kk = g & 1;
            bf16x8 af[4], bfr[4];
#pragma unroll
            for (int m = 0; m < 4; ++m) {
                int row = wr * 64 + m * 16 + lr;
                af[m] = as_bf(*(const u16x8*)(&Aa[row * 64 + (((kk * 4 + lg) ^ (lr & 7)) << 3)]));
            }
#pragma unroll
            for (int n = 0; n < 4; ++n) {
                int row = wc * 64 + n * 16 + lr;
                bfr[n] = as_bf(*(const u16x8*)(&Ba[row * 64 + (((kk * 4 + lg) ^ (lr & 7)) << 3)]));
            }
#pragma unroll
            for (int m = 0; m < 4; ++m)
#pragma unroll
                for (int n = 0; n < 4; ++n)
                    acc[m][n] = __builtin_amdgcn_mfma_f32_16x16x32_bf16(af[m], bfr[n], acc[m][n], 0, 0, 0);
        }
    }
    // epilogue: multiply by 1/rowsum, store f32
#pragma unroll
    for (int m = 0; m < 4; ++m) {
#pragma unroll
        for (int r = 0; r < 4; ++r) {
            int rloc = wr * 64 + m * 16 + lg * 4 + r;
            float rl = rl_s[rloc];
#pragma unroll
            for (int n = 0; n < 4; ++n)
                Out[(size_t)(q0 + rloc) * 1024 + e0 + wc * 64 + n * 16 + lr] = acc[m][n][r] * rl;
        }
    }
}

// ---------------------------------------------------------------------------
extern "C" void kernel_launch(void* const* d_in, const int* in_sizes, int n_in,
                              void* d_out, int out_size, void* d_ws, size_t ws_size,
                              hipStream_t stream) {
    const float* x  = (const float*)d_in[0];
    const float* Wq = (const float*)d_in[1];
    const float* Wk = (const float*)d_in[2];
    const float* Wv = (const float*)d_in[3];
    float* out = (float*)d_out;

    char* ws = (char*)d_ws;
    u16*   Wt  = (u16*)(ws);                     //  6,291,456 B
    u16*   Qb  = (u16*)(ws + 6291456);           //  8,388,608 B
    u16*   Kb  = (u16*)(ws + 14680064);          //  8,388,608 B
    u16*   V0  = (u16*)(ws + 23068672);          //  8,388,608 B
    u16*   V1  = (u16*)(ws + 31457280);          //  8,388,608 B
    u16*   P0  = (u16*)(ws + 39845888);          // 33,554,432 B
    u16*   P1  = (u16*)(ws + 73400320);          // 33,554,432 B
    float* plg = (float*)(ws + 106954752);       //  2,097,152 B (total 109,051,904 - proven in r10)

    wt_kernel<<<dim3(16, 16, 3), 256, 0, stream>>>(Wq, Wk, Wv, Wt);
    for (int p = 0; p < 2; ++p) {
        const float* x0 = x + (size_t)(2 * p) * 4194304;
        const float* x1 = x + (size_t)(2 * p + 1) * 4194304;
        float* o0 = out + (size_t)(2 * p) * 4194304;
        float* o1 = out + (size_t)(2 * p + 1) * 4194304;
        qkv_gemm<<<dim3(768), 256, 0, stream>>>(x0, Wt, Qb, Kb, V0);
        qk_gemm<<<dim3(1024), 256, 0, stream>>>(Qb, Kb, P0, plg);
        qkv_gemm<<<dim3(768), 256, 0, stream>>>(x1, Wt, Qb, Kb, V1);
        qk_gemm<<<dim3(1024), 256, 0, stream>>>(Qb, Kb, P1, plg + 262144);
        pv_pair<<<dim3(512), 256, 0, stream>>>(P0, P1, V0, V1, plg, o0, o1);
    }
}

// Round 15
// 450.055 us; speedup vs baseline: 1.3240x; 1.0264x over previous
//
#include <hip/hip_runtime.h>

typedef unsigned short u16;
typedef float f32x4 __attribute__((ext_vector_type(4)));
typedef u16   u16x4 __attribute__((ext_vector_type(4)));
typedef u16   u16x8 __attribute__((ext_vector_type(8)));
typedef __bf16 bf16x8 __attribute__((ext_vector_type(8)));

static __device__ __forceinline__ u16 f2bf(float x) {
    unsigned int u = __builtin_bit_cast(unsigned int, x);
    u = (u + 0x7FFFu + ((u >> 16) & 1u)) >> 16;
    return (u16)u;
}
static __device__ __forceinline__ float bf2f(u16 x) {
    unsigned int u = ((unsigned int)x) << 16;
    return __builtin_bit_cast(float, u);
}
static __device__ __forceinline__ bf16x8 as_bf(u16x8 v) { return __builtin_bit_cast(bf16x8, v); }

// async global->LDS, 16B per lane; LDS dest = wave-uniform base + lane*16
static __device__ __forceinline__ void gload16(const u16* g, u16* lds) {
    __builtin_amdgcn_global_load_lds(
        (const __attribute__((address_space(1))) void*)g,
        (__attribute__((address_space(3))) void*)lds,
        16, 0, 0);
}

#define KSCALE 0.045084220027780106f   /* log2(e)/32 */

// Stage a [128 x 64] u16 tile into LDS; read-side XOR swizzle baked into the
// per-lane GLOBAL address (LDS image = linear dest, swizzled source).
// PROVEN zero-conflict with the matching read pattern (rounds 5-14).
#define STAGE_G2L(dst, src, stride, ROUNDS) do {                               \
    _Pragma("unroll") for (int i_ = 0; i_ < (ROUNDS); ++i_) {                  \
        int c_ = (i_ * 4 + w) * 64 + l;                                        \
        int row_ = c_ >> 3, c8_ = c_ & 7;                                      \
        gload16((src) + (size_t)row_ * (stride) + ((c8_ ^ (row_ & 7)) << 3),   \
                &(dst)[(i_ * 4 + w) * 512]);                                   \
    } } while (0)

// ---------------------------------------------------------------------------
// Kernel 1: W [1024 d_in][1024 d_out] fp32  ->  Wt [mat][1024 d_out][1024 d_in] bf16
// ---------------------------------------------------------------------------
__global__ __launch_bounds__(256) void wt_kernel(const float* __restrict__ Wq,
                                                 const float* __restrict__ Wk,
                                                 const float* __restrict__ Wv,
                                                 u16* __restrict__ Wt) {
    __shared__ float tile[64][65];
    const int mat = blockIdx.z;
    const float* W = (mat == 0) ? Wq : ((mat == 1) ? Wk : Wv);
    const int bx = blockIdx.x, by = blockIdx.y;
    const int tid = threadIdx.x;
#pragma unroll
    for (int i = 0; i < 16; ++i) {
        int idx = i * 256 + tid;
        int r = idx >> 6, c = idx & 63;
        tile[r][c] = W[(by * 64 + r) * 1024 + bx * 64 + c];
    }
    __syncthreads();
#pragma unroll
    for (int i = 0; i < 16; ++i) {
        int idx = i * 256 + tid;
        int r = idx >> 6, c = idx & 63;
        Wt[mat * 1048576 + (bx * 64 + r) * 1024 + by * 64 + c] = f2bf(tile[c][r]);
    }
}

// ---------------------------------------------------------------------------
// Kernel 2: QKV GEMM, nb batches per dispatch (grid = nb*768).
// C[4096][3072] = X_bb * Wt^T. Q,K row-major bf16; V -> Vt[1024 e][4096 k].
// Body verbatim round-10-proven; only the preamble selects the batch.
// ---------------------------------------------------------------------------
__global__ __launch_bounds__(256, 3) void qkv_gemm(const float* __restrict__ X0,
                                                   const float* __restrict__ X1,
                                                   const u16* __restrict__ Wt,
                                                   u16* __restrict__ Q0o, u16* __restrict__ K0o, u16* __restrict__ V0o,
                                                   u16* __restrict__ Q1o, u16* __restrict__ K1o, u16* __restrict__ V1o,
                                                   int nb) {
    __shared__ u16 As[128 * 64];
    __shared__ u16 Bs[128 * 64];
    const int bid = blockIdx.x;
    const int swz = (bid & 7) * (nb * 96) + (bid >> 3);   // XCD-bijective, nwg%8==0
    const int bb = (swz >= 768) ? 1 : 0;
    const int rem = swz - bb * 768;
    const int bm = rem / 24, bn = rem % 24;
    const float* X = bb ? X1 : X0;
    u16* Qo = bb ? Q1o : Q0o;
    u16* Ko = bb ? K1o : K0o;
    u16* Vt = bb ? V1o : V0o;
    const int tid = threadIdx.x;
    const int w = tid >> 6, l = tid & 63, lg = l >> 4, lr = l & 15;
    const int wr = w >> 1, wc = w & 1;

    const f32x4 z4 = {0.f, 0.f, 0.f, 0.f};
    f32x4 acc[4][4];
#pragma unroll
    for (int m = 0; m < 4; ++m)
#pragma unroll
        for (int n = 0; n < 4; ++n) acc[m][n] = z4;

    for (int kb = 0; kb < 16; ++kb) {
        __syncthreads();
        STAGE_G2L(Bs, Wt + (size_t)(bn * 128) * 1024 + kb * 64, 1024, 4);
#pragma unroll
        for (int i = 0; i < 4; ++i) {
            int cid = i * 256 + tid;
            int row = cid >> 3, c8 = cid & 7;
            const float* src = X + (bm * 128 + row) * 1024 + kb * 64 + c8 * 8;
            f32x4 v0 = *(const f32x4*)(src);
            f32x4 v1 = *(const f32x4*)(src + 4);
            u16x8 t;
            t[0] = f2bf(v0[0]); t[1] = f2bf(v0[1]); t[2] = f2bf(v0[2]); t[3] = f2bf(v0[3]);
            t[4] = f2bf(v1[0]); t[5] = f2bf(v1[1]); t[6] = f2bf(v1[2]); t[7] = f2bf(v1[3]);
            *(u16x8*)(&As[row * 64 + ((c8 ^ (row & 7)) << 3)]) = t;
        }
        __syncthreads();
#pragma unroll
        for (int kk = 0; kk < 2; ++kk) {
            bf16x8 af[4], bfr[4];
#pragma unroll
            for (int m = 0; m < 4; ++m) {
                int row = wr * 64 + m * 16 + lr;
                af[m] = as_bf(*(const u16x8*)(&As[row * 64 + (((kk * 4 + lg) ^ (lr & 7)) << 3)]));
            }
#pragma unroll
            for (int n = 0; n < 4; ++n) {
                int row = wc * 64 + n * 16 + lr;
                bfr[n] = as_bf(*(const u16x8*)(&Bs[row * 64 + (((kk * 4 + lg) ^ (lr & 7)) << 3)]));
            }
#pragma unroll
            for (int m = 0; m < 4; ++m)
#pragma unroll
                for (int n = 0; n < 4; ++n)
                    acc[m][n] = __builtin_amdgcn_mfma_f32_16x16x32_bf16(af[m], bfr[n], acc[m][n], 0, 0, 0);
        }
    }
    const int row0 = bm * 128 + wr * 64;
    const int col0 = bn * 128 + wc * 64;
#pragma unroll
    for (int m = 0; m < 4; ++m) {
#pragma unroll
        for (int n = 0; n < 4; ++n) {
            int col = col0 + n * 16 + lr;
            int mat = col >> 10;
            int cg = col & 1023;
            int row = row0 + m * 16 + lg * 4;
            if (mat == 2) {
                u16x4 v;
                v[0] = f2bf(acc[m][n][0]); v[1] = f2bf(acc[m][n][1]);
                v[2] = f2bf(acc[m][n][2]); v[3] = f2bf(acc[m][n][3]);
                *(u16x4*)(Vt + cg * 4096 + row) = v;
            } else {
                u16* P = mat ? Ko : Qo;
#pragma unroll
                for (int r = 0; r < 4; ++r) P[(row + r) * 1024 + cg] = f2bf(acc[m][n][r]);
            }
        }
    }
}

// ---------------------------------------------------------------------------
// Kernel 3: QK^T GEMM, nb batches per dispatch (grid = nb*1024).
// P_bb[4096 q][4096 k] bf16 = exp2(QK^T * c), plus per-row partial sums
// pl[bb*262144 + row*64 + bn*2 + wc]. Body verbatim round-10-proven.
// ---------------------------------------------------------------------------
__global__ __launch_bounds__(256, 4) void qk_gemm(const u16* __restrict__ Q0b, const u16* __restrict__ K0b, u16* __restrict__ P0,
                                                  const u16* __restrict__ Q1b, const u16* __restrict__ K1b, u16* __restrict__ P1,
                                                  float* __restrict__ pl, int nb) {
    __shared__ u16 As[128 * 64];
    __shared__ u16 Bs[128 * 64];
    const int bid = blockIdx.x;
    const int swz = (bid & 7) * (nb * 128) + (bid >> 3);  // XCD-bijective
    const int bb = swz >> 10;
    const int rem = swz & 1023;
    const int bm = rem >> 5, bn = rem & 31;
    const u16* Qb = bb ? Q1b : Q0b;
    const u16* Kb = bb ? K1b : K0b;
    u16* P = bb ? P1 : P0;
    float* plb = pl + (size_t)bb * 262144;
    const int tid = threadIdx.x;
    const int w = tid >> 6, l = tid & 63, lg = l >> 4, lr = l & 15;
    const int wr = w >> 1, wc = w & 1;

    const f32x4 z4 = {0.f, 0.f, 0.f, 0.f};
    f32x4 acc[4][4];
#pragma unroll
    for (int m = 0; m < 4; ++m)
#pragma unroll
        for (int n = 0; n < 4; ++n) acc[m][n] = z4;

    for (int kb = 0; kb < 16; ++kb) {
        __syncthreads();
        STAGE_G2L(As, Qb + (size_t)(bm * 128) * 1024 + kb * 64, 1024, 4);
        STAGE_G2L(Bs, Kb + (size_t)(bn * 128) * 1024 + kb * 64, 1024, 4);
        __syncthreads();
#pragma unroll
        for (int kk = 0; kk < 2; ++kk) {
            bf16x8 af[4], bfr[4];
#pragma unroll
            for (int m = 0; m < 4; ++m) {
                int row = wr * 64 + m * 16 + lr;
                af[m] = as_bf(*(const u16x8*)(&As[row * 64 + (((kk * 4 + lg) ^ (lr & 7)) << 3)]));
            }
#pragma unroll
            for (int n = 0; n < 4; ++n) {
                int row = wc * 64 + n * 16 + lr;
                bfr[n] = as_bf(*(const u16x8*)(&Bs[row * 64 + (((kk * 4 + lg) ^ (lr & 7)) << 3)]));
            }
#pragma unroll
            for (int m = 0; m < 4; ++m)
#pragma unroll
                for (int n = 0; n < 4; ++n)
                    acc[m][n] = __builtin_amdgcn_mfma_f32_16x16x32_bf16(af[m], bfr[n], acc[m][n], 0, 0, 0);
        }
    }
    const int row0 = bm * 128 + wr * 64;
    const int col0 = bn * 128 + wc * 64;
#pragma unroll
    for (int m = 0; m < 4; ++m) {
#pragma unroll
        for (int r = 0; r < 4; ++r) {
            const size_t rowg = (size_t)(row0 + m * 16 + lg * 4 + r);
            float se = 0.f;
#pragma unroll
            for (int n = 0; n < 4; ++n) {
                u16 pb = f2bf(exp2f(acc[m][n][r] * KSCALE));
                P[rowg * 4096 + col0 + n * 16 + lr] = pb;
                se += bf2f(pb);
            }
            se += __shfl_xor(se, 1, 64);
            se += __shfl_xor(se, 2, 64);
            se += __shfl_xor(se, 4, 64);
            se += __shfl_xor(se, 8, 64);
            if (lr == 0) plb[rowg * 64 + bn * 2 + wc] = se;
        }
    }
}

// ---------------------------------------------------------------------------
// Kernel 4: pair-fused PV GEMM, BK=128 via SPLIT ARRAYS (round-14 proven,
// zero conflicts). O_bb = (P_bb * V_bb) / rowsum.
// ---------------------------------------------------------------------------
__global__ __launch_bounds__(256, 2) void pv_pair(const u16* __restrict__ P0,
                                                  const u16* __restrict__ P1,
                                                  const u16* __restrict__ V0,
                                                  const u16* __restrict__ V1,
                                                  const float* __restrict__ pl,
                                                  float* __restrict__ Out0,
                                                  float* __restrict__ Out1) {
    __shared__ u16 As0[128 * 64];
    __shared__ u16 As1[128 * 64];
    __shared__ u16 Bs0[128 * 64];
    __shared__ u16 Bs1[128 * 64];
    __shared__ float rl_s[128];
    const int bid = blockIdx.x;
    const int swz = (bid & 7) * 64 + (bid >> 3);   // 512 blocks, XCD-bijective
    const int bb = swz >> 8, rem = swz & 255;
    const int bm = rem >> 3, bn = rem & 7;
    const int q0 = bm * 128, e0 = bn * 128;
    const u16* P  = bb ? P1 : P0;
    const u16* Vt = bb ? V1 : V0;
    float* Out    = bb ? Out1 : Out0;
    const int tid = threadIdx.x;
    const int w = tid >> 6, l = tid & 63, lg = l >> 4, lr = l & 15;
    const int wr = w >> 1, wc = w & 1;

    if (tid < 128) {
        const f32x4* pp = (const f32x4*)(pl + (size_t)(bb * 4096 + q0 + tid) * 64);
        f32x4 a = pp[0];
#pragma unroll
        for (int i = 1; i < 16; ++i) a += pp[i];
        rl_s[tid] = 1.0f / (a[0] + a[1] + a[2] + a[3]);
    }

    const f32x4 z4 = {0.f, 0.f, 0.f, 0.f};
    f32x4 acc[4][4];
#pragma unroll
    for (int m = 0; m < 4; ++m)
#pragma unroll
        for (int n = 0; n < 4; ++n) acc[m][n] = z4;

    for (int kb = 0; kb < 32; ++kb) {
        __syncthreads();
        STAGE_G2L(As0, P  + (size_t)q0 * 4096 + kb * 128,      4096, 4);
        STAGE_G2L(As1, P  + (size_t)q0 * 4096 + kb * 128 + 64, 4096, 4);
        STAGE_G2L(Bs0, Vt + (size_t)e0 * 4096 + kb * 128,      4096, 4);
        STAGE_G2L(Bs1, Vt + (size_t)e0 * 4096 + kb * 128 + 64, 4096, 4);
        __syncthreads();
#pragma unroll
        for (int g = 0; g < 4; ++g) {
            const u16* Aa = (g < 2) ? As0 : As1;
            const u16* Ba = (g < 2) ? Bs0 : Bs1;
            const int kk = g & 1;
            bf16x8 af[4], bfr[4];
#pragma unroll
            for (int m = 0; m < 4; ++m) {
                int row = wr * 64 + m * 16 + lr;
                af[m] = as_bf(*(const u16x8*)(&Aa[row * 64 + (((kk * 4 + lg) ^ (lr & 7)) << 3)]));
            }
#pragma unroll
            for (int n = 0; n < 4; ++n) {
                int row = wc * 64 + n * 16 + lr;
                bfr[n] = as_bf(*(const u16x8*)(&Ba[row * 64 + (((kk * 4 + lg) ^ (lr & 7)) << 3)]));
            }
#pragma unroll
            for (int m = 0; m < 4; ++m)
#pragma unroll
                for (int n = 0; n < 4; ++n)
                    acc[m][n] = __builtin_amdgcn_mfma_f32_16x16x32_bf16(af[m], bfr[n], acc[m][n], 0, 0, 0);
        }
    }
    // epilogue: multiply by 1/rowsum, store f32
#pragma unroll
    for (int m = 0; m < 4; ++m) {
#pragma unroll
        for (int r = 0; r < 4; ++r) {
            int rloc = wr * 64 + m * 16 + lg * 4 + r;
            float rl = rl_s[rloc];
#pragma unroll
            for (int n = 0; n < 4; ++n)
                Out[(size_t)(q0 + rloc) * 1024 + e0 + wc * 64 + n * 16 + lr] = acc[m][n][r] * rl;
        }
    }
}

// ---------------------------------------------------------------------------
extern "C" void kernel_launch(void* const* d_in, const int* in_sizes, int n_in,
                              void* d_out, int out_size, void* d_ws, size_t ws_size,
                              hipStream_t stream) {
    const float* x  = (const float*)d_in[0];
    const float* Wq = (const float*)d_in[1];
    const float* Wk = (const float*)d_in[2];
    const float* Wv = (const float*)d_in[3];
    float* out = (float*)d_out;
    char* ws = (char*)d_ws;

    // ws_size is fixed across calls -> branch is deterministic.
    const bool big = (ws_size >= 125829120u);

    wt_kernel<<<dim3(16, 16, 3), 256, 0, stream>>>(Wq, Wk, Wv, (u16*)ws);

    if (big) {
        // merged-pair layout (120 MB): 7 dispatches total
        u16*   Wt  = (u16*)(ws);                   //   6,291,456
        u16*   Q0  = (u16*)(ws + 6291456);         //   8,388,608
        u16*   K0  = (u16*)(ws + 14680064);        //   8,388,608
        u16*   Q1  = (u16*)(ws + 23068672);        //   8,388,608
        u16*   K1  = (u16*)(ws + 31457280);        //   8,388,608
        u16*   V0  = (u16*)(ws + 39845888);        //   8,388,608
        u16*   V1  = (u16*)(ws + 48234496);        //   8,388,608
        u16*   P0  = (u16*)(ws + 56623104);        //  33,554,432
        u16*   P1  = (u16*)(ws + 90177536);        //  33,554,432
        float* plg = (float*)(ws + 123731968);     //   2,097,152  (= 125,829,120)
        for (int p = 0; p < 2; ++p) {
            const float* x0 = x + (size_t)(2 * p) * 4194304;
            const float* x1 = x + (size_t)(2 * p + 1) * 4194304;
            float* o0 = out + (size_t)(2 * p) * 4194304;
            float* o1 = out + (size_t)(2 * p + 1) * 4194304;
            qkv_gemm<<<dim3(1536), 256, 0, stream>>>(x0, x1, Wt, Q0, K0, V0, Q1, K1, V1, 2);
            qk_gemm<<<dim3(2048), 256, 0, stream>>>(Q0, K0, P0, Q1, K1, P1, plg, 2);
            pv_pair<<<dim3(512), 256, 0, stream>>>(P0, P1, V0, V1, plg, o0, o1);
        }
    } else {
        // round-14 proven layout (109 MB): 11 dispatches
        u16*   Wt  = (u16*)(ws);
        u16*   Qb  = (u16*)(ws + 6291456);
        u16*   Kb  = (u16*)(ws + 14680064);
        u16*   V0  = (u16*)(ws + 23068672);
        u16*   V1  = (u16*)(ws + 31457280);
        u16*   P0  = (u16*)(ws + 39845888);
        u16*   P1  = (u16*)(ws + 73400320);
        float* plg = (float*)(ws + 106954752);
        for (int p = 0; p < 2; ++p) {
            const float* x0 = x + (size_t)(2 * p) * 4194304;
            const float* x1 = x + (size_t)(2 * p + 1) * 4194304;
            float* o0 = out + (size_t)(2 * p) * 4194304;
            float* o1 = out + (size_t)(2 * p + 1) * 4194304;
            qkv_gemm<<<dim3(768), 256, 0, stream>>>(x0, x0, Wt, Qb, Kb, V0, Qb, Kb, V0, 1);
            qk_gemm<<<dim3(1024), 256, 0, stream>>>(Qb, Kb, P0, Qb, Kb, P0, plg, 1);
            qkv_gemm<<<dim3(768), 256, 0, stream>>>(x1, x1, Wt, Qb, Kb, V1, Qb, Kb, V1, 1);
            qk_gemm<<<dim3(1024), 256, 0, stream>>>(Qb, Kb, P1, Qb, Kb, P1, plg + 262144, 1);
            pv_pair<<<dim3(512), 256, 0, stream>>>(P0, P1, V0, V1, plg, o0, o1);
        }
    }
}

// Round 16
// 410.501 us; speedup vs baseline: 1.4516x; 1.0964x over previous
//
#include <hip/hip_runtime.h>

typedef unsigned short u16;
typedef float f32x4 __attribute__((ext_vector_type(4)));
typedef u16   u16x4 __attribute__((ext_vector_type(4)));
typedef u16   u16x8 __attribute__((ext_vector_type(8)));
typedef __bf16 bf16x8 __attribute__((ext_vector_type(8)));

static __device__ __forceinline__ u16 f2bf(float x) {
    unsigned int u = __builtin_bit_cast(unsigned int, x);
    u = (u + 0x7FFFu + ((u >> 16) & 1u)) >> 16;
    return (u16)u;
}
static __device__ __forceinline__ float bf2f(u16 x) {
    unsigned int u = ((unsigned int)x) << 16;
    return __builtin_bit_cast(float, u);
}
static __device__ __forceinline__ bf16x8 as_bf(u16x8 v) { return __builtin_bit_cast(bf16x8, v); }

// async global->LDS, 16B per lane; LDS dest = wave-uniform base + lane*16
static __device__ __forceinline__ void gload16(const u16* g, u16* lds) {
    __builtin_amdgcn_global_load_lds(
        (const __attribute__((address_space(1))) void*)g,
        (__attribute__((address_space(3))) void*)lds,
        16, 0, 0);
}

#define KSCALE 0.045084220027780106f   /* log2(e)/32 */

// Stage a [128 x 64] u16 tile into LDS; read-side XOR swizzle baked into the
// per-lane GLOBAL address (LDS image = linear dest, swizzled source).
// PROVEN zero-conflict with the matching read pattern (rounds 5-15).
#define STAGE_G2L(dst, src, stride, ROUNDS) do {                               \
    _Pragma("unroll") for (int i_ = 0; i_ < (ROUNDS); ++i_) {                  \
        int c_ = (i_ * 4 + w) * 64 + l;                                        \
        int row_ = c_ >> 3, c8_ = c_ & 7;                                      \
        gload16((src) + (size_t)row_ * (stride) + ((c8_ ^ (row_ & 7)) << 3),   \
                &(dst)[(i_ * 4 + w) * 512]);                                   \
    } } while (0)

// ---------------------------------------------------------------------------
// Kernel 0: X fp32 -> bf16 copy (2 batches / dispatch; pure streaming).
// Removes the 24x-redundant in-GEMM conversion (round-5 pv lesson, again).
// ---------------------------------------------------------------------------
__global__ __launch_bounds__(256) void xconv(const float* __restrict__ X0,
                                             const float* __restrict__ X1,
                                             u16* __restrict__ Xb0,
                                             u16* __restrict__ Xb1) {
    const int b = blockIdx.x >> 11;            // 2048 blocks per batch
    const int blk = blockIdx.x & 2047;
    const float* X = b ? X1 : X0;
    u16* Xb = b ? Xb1 : Xb0;
    const size_t base = (size_t)blk * 2048 + (size_t)threadIdx.x * 8;
    f32x4 v0 = *(const f32x4*)(X + base);
    f32x4 v1 = *(const f32x4*)(X + base + 4);
    u16x8 t;
    t[0] = f2bf(v0[0]); t[1] = f2bf(v0[1]); t[2] = f2bf(v0[2]); t[3] = f2bf(v0[3]);
    t[4] = f2bf(v1[0]); t[5] = f2bf(v1[1]); t[6] = f2bf(v1[2]); t[7] = f2bf(v1[3]);
    *(u16x8*)(Xb + base) = t;
}

// ---------------------------------------------------------------------------
// Kernel 1: W [1024 d_in][1024 d_out] fp32  ->  Wt [mat][1024 d_out][1024 d_in] bf16
// ---------------------------------------------------------------------------
__global__ __launch_bounds__(256) void wt_kernel(const float* __restrict__ Wq,
                                                 const float* __restrict__ Wk,
                                                 const float* __restrict__ Wv,
                                                 u16* __restrict__ Wt) {
    __shared__ float tile[64][65];
    const int mat = blockIdx.z;
    const float* W = (mat == 0) ? Wq : ((mat == 1) ? Wk : Wv);
    const int bx = blockIdx.x, by = blockIdx.y;
    const int tid = threadIdx.x;
#pragma unroll
    for (int i = 0; i < 16; ++i) {
        int idx = i * 256 + tid;
        int r = idx >> 6, c = idx & 63;
        tile[r][c] = W[(by * 64 + r) * 1024 + bx * 64 + c];
    }
    __syncthreads();
#pragma unroll
    for (int i = 0; i < 16; ++i) {
        int idx = i * 256 + tid;
        int r = idx >> 6, c = idx & 63;
        Wt[mat * 1048576 + (bx * 64 + r) * 1024 + by * 64 + c] = f2bf(tile[c][r]);
    }
}

// ---------------------------------------------------------------------------
// Kernel 2: QKV GEMM, nb batches/dispatch (grid = nb*768), BOTH operands
// bf16 gload-staged (structurally identical to the proven qk_gemm).
// C[4096][3072] = Xb_bb * Wt^T. Q,K row-major bf16; V -> Vt[1024 e][4096 k].
// ---------------------------------------------------------------------------
__global__ __launch_bounds__(256, 4) void qkv_gemm(const u16* __restrict__ X0b,
                                                   const u16* __restrict__ X1b,
                                                   const u16* __restrict__ Wt,
                                                   u16* __restrict__ Q0o, u16* __restrict__ K0o, u16* __restrict__ V0o,
                                                   u16* __restrict__ Q1o, u16* __restrict__ K1o, u16* __restrict__ V1o,
                                                   int nb) {
    __shared__ u16 As[128 * 64];
    __shared__ u16 Bs[128 * 64];
    const int bid = blockIdx.x;
    const int swz = (bid & 7) * (nb * 96) + (bid >> 3);   // XCD-bijective
    const int bb = (swz >= 768) ? 1 : 0;
    const int rem = swz - bb * 768;
    const int bm = rem / 24, bn = rem % 24;
    const u16* Xb = bb ? X1b : X0b;
    u16* Qo = bb ? Q1o : Q0o;
    u16* Ko = bb ? K1o : K0o;
    u16* Vt = bb ? V1o : V0o;
    const int tid = threadIdx.x;
    const int w = tid >> 6, l = tid & 63, lg = l >> 4, lr = l & 15;
    const int wr = w >> 1, wc = w & 1;

    const f32x4 z4 = {0.f, 0.f, 0.f, 0.f};
    f32x4 acc[4][4];
#pragma unroll
    for (int m = 0; m < 4; ++m)
#pragma unroll
        for (int n = 0; n < 4; ++n) acc[m][n] = z4;

    for (int kb = 0; kb < 16; ++kb) {
        __syncthreads();
        STAGE_G2L(As, Xb + (size_t)(bm * 128) * 1024 + kb * 64, 1024, 4);
        STAGE_G2L(Bs, Wt + (size_t)(bn * 128) * 1024 + kb * 64, 1024, 4);
        __syncthreads();
#pragma unroll
        for (int kk = 0; kk < 2; ++kk) {
            bf16x8 af[4], bfr[4];
#pragma unroll
            for (int m = 0; m < 4; ++m) {
                int row = wr * 64 + m * 16 + lr;
                af[m] = as_bf(*(const u16x8*)(&As[row * 64 + (((kk * 4 + lg) ^ (lr & 7)) << 3)]));
            }
#pragma unroll
            for (int n = 0; n < 4; ++n) {
                int row = wc * 64 + n * 16 + lr;
                bfr[n] = as_bf(*(const u16x8*)(&Bs[row * 64 + (((kk * 4 + lg) ^ (lr & 7)) << 3)]));
            }
#pragma unroll
            for (int m = 0; m < 4; ++m)
#pragma unroll
                for (int n = 0; n < 4; ++n)
                    acc[m][n] = __builtin_amdgcn_mfma_f32_16x16x32_bf16(af[m], bfr[n], acc[m][n], 0, 0, 0);
        }
    }
    const int row0 = bm * 128 + wr * 64;
    const int col0 = bn * 128 + wc * 64;
#pragma unroll
    for (int m = 0; m < 4; ++m) {
#pragma unroll
        for (int n = 0; n < 4; ++n) {
            int col = col0 + n * 16 + lr;
            int mat = col >> 10;
            int cg = col & 1023;
            int row = row0 + m * 16 + lg * 4;
            if (mat == 2) {
                u16x4 v;
                v[0] = f2bf(acc[m][n][0]); v[1] = f2bf(acc[m][n][1]);
                v[2] = f2bf(acc[m][n][2]); v[3] = f2bf(acc[m][n][3]);
                *(u16x4*)(Vt + cg * 4096 + row) = v;
            } else {
                u16* P = mat ? Ko : Qo;
#pragma unroll
                for (int r = 0; r < 4; ++r) P[(row + r) * 1024 + cg] = f2bf(acc[m][n][r]);
            }
        }
    }
}

// ---------------------------------------------------------------------------
// Kernel 3: QK^T GEMM, nb batches/dispatch (grid = nb*1024).
// P_bb[4096 q][4096 k] bf16 = exp2(QK^T * c) + per-row partial sums pl.
// ---------------------------------------------------------------------------
__global__ __launch_bounds__(256, 4) void qk_gemm(const u16* __restrict__ Q0b, const u16* __restrict__ K0b, u16* __restrict__ P0,
                                                  const u16* __restrict__ Q1b, const u16* __restrict__ K1b, u16* __restrict__ P1,
                                                  float* __restrict__ pl, int nb) {
    __shared__ u16 As[128 * 64];
    __shared__ u16 Bs[128 * 64];
    const int bid = blockIdx.x;
    const int swz = (bid & 7) * (nb * 128) + (bid >> 3);  // XCD-bijective
    const int bb = swz >> 10;
    const int rem = swz & 1023;
    const int bm = rem >> 5, bn = rem & 31;
    const u16* Qb = bb ? Q1b : Q0b;
    const u16* Kb = bb ? K1b : K0b;
    u16* P = bb ? P1 : P0;
    float* plb = pl + (size_t)bb * 262144;
    const int tid = threadIdx.x;
    const int w = tid >> 6, l = tid & 63, lg = l >> 4, lr = l & 15;
    const int wr = w >> 1, wc = w & 1;

    const f32x4 z4 = {0.f, 0.f, 0.f, 0.f};
    f32x4 acc[4][4];
#pragma unroll
    for (int m = 0; m < 4; ++m)
#pragma unroll
        for (int n = 0; n < 4; ++n) acc[m][n] = z4;

    for (int kb = 0; kb < 16; ++kb) {
        __syncthreads();
        STAGE_G2L(As, Qb + (size_t)(bm * 128) * 1024 + kb * 64, 1024, 4);
        STAGE_G2L(Bs, Kb + (size_t)(bn * 128) * 1024 + kb * 64, 1024, 4);
        __syncthreads();
#pragma unroll
        for (int kk = 0; kk < 2; ++kk) {
            bf16x8 af[4], bfr[4];
#pragma unroll
            for (int m = 0; m < 4; ++m) {
                int row = wr * 64 + m * 16 + lr;
                af[m] = as_bf(*(const u16x8*)(&As[row * 64 + (((kk * 4 + lg) ^ (lr & 7)) << 3)]));
            }
#pragma unroll
            for (int n = 0; n < 4; ++n) {
                int row = wc * 64 + n * 16 + lr;
                bfr[n] = as_bf(*(const u16x8*)(&Bs[row * 64 + (((kk * 4 + lg) ^ (lr & 7)) << 3)]));
            }
#pragma unroll
            for (int m = 0; m < 4; ++m)
#pragma unroll
                for (int n = 0; n < 4; ++n)
                    acc[m][n] = __builtin_amdgcn_mfma_f32_16x16x32_bf16(af[m], bfr[n], acc[m][n], 0, 0, 0);
        }
    }
    const int row0 = bm * 128 + wr * 64;
    const int col0 = bn * 128 + wc * 64;
#pragma unroll
    for (int m = 0; m < 4; ++m) {
#pragma unroll
        for (int r = 0; r < 4; ++r) {
            const size_t rowg = (size_t)(row0 + m * 16 + lg * 4 + r);
            float se = 0.f;
#pragma unroll
            for (int n = 0; n < 4; ++n) {
                u16 pb = f2bf(exp2f(acc[m][n][r] * KSCALE));
                P[rowg * 4096 + col0 + n * 16 + lr] = pb;
                se += bf2f(pb);
            }
            se += __shfl_xor(se, 1, 64);
            se += __shfl_xor(se, 2, 64);
            se += __shfl_xor(se, 4, 64);
            se += __shfl_xor(se, 8, 64);
            if (lr == 0) plb[rowg * 64 + bn * 2 + wc] = se;
        }
    }
}

// ---------------------------------------------------------------------------
// Kernel 4: pair-fused PV GEMM, BK=128 via SPLIT ARRAYS (round-14 proven,
// zero conflicts). O_bb = (P_bb * V_bb) / rowsum.
// ---------------------------------------------------------------------------
__global__ __launch_bounds__(256, 2) void pv_pair(const u16* __restrict__ P0,
                                                  const u16* __restrict__ P1,
                                                  const u16* __restrict__ V0,
                                                  const u16* __restrict__ V1,
                                                  const float* __restrict__ pl,
                                                  float* __restrict__ Out0,
                                                  float* __restrict__ Out1) {
    __shared__ u16 As0[128 * 64];
    __shared__ u16 As1[128 * 64];
    __shared__ u16 Bs0[128 * 64];
    __shared__ u16 Bs1[128 * 64];
    __shared__ float rl_s[128];
    const int bid = blockIdx.x;
    const int swz = (bid & 7) * 64 + (bid >> 3);   // 512 blocks, XCD-bijective
    const int bb = swz >> 8, rem = swz & 255;
    const int bm = rem >> 3, bn = rem & 7;
    const int q0 = bm * 128, e0 = bn * 128;
    const u16* P  = bb ? P1 : P0;
    const u16* Vt = bb ? V1 : V0;
    float* Out    = bb ? Out1 : Out0;
    const int tid = threadIdx.x;
    const int w = tid >> 6, l = tid & 63, lg = l >> 4, lr = l & 15;
    const int wr = w >> 1, wc = w & 1;

    if (tid < 128) {
        const f32x4* pp = (const f32x4*)(pl + (size_t)(bb * 4096 + q0 + tid) * 64);
        f32x4 a = pp[0];
#pragma unroll
        for (int i = 1; i < 16; ++i) a += pp[i];
        rl_s[tid] = 1.0f / (a[0] + a[1] + a[2] + a[3]);
    }

    const f32x4 z4 = {0.f, 0.f, 0.f, 0.f};
    f32x4 acc[4][4];
#pragma unroll
    for (int m = 0; m < 4; ++m)
#pragma unroll
        for (int n = 0; n < 4; ++n) acc[m][n] = z4;

    for (int kb = 0; kb < 32; ++kb) {
        __syncthreads();
        STAGE_G2L(As0, P  + (size_t)q0 * 4096 + kb * 128,      4096, 4);
        STAGE_G2L(As1, P  + (size_t)q0 * 4096 + kb * 128 + 64, 4096, 4);
        STAGE_G2L(Bs0, Vt + (size_t)e0 * 4096 + kb * 128,      4096, 4);
        STAGE_G2L(Bs1, Vt + (size_t)e0 * 4096 + kb * 128 + 64, 4096, 4);
        __syncthreads();
#pragma unroll
        for (int g = 0; g < 4; ++g) {
            const u16* Aa = (g < 2) ? As0 : As1;
            const u16* Ba = (g < 2) ? Bs0 : Bs1;
            const int kk = g & 1;
            bf16x8 af[4], bfr[4];
#pragma unroll
            for (int m = 0; m < 4; ++m) {
                int row = wr * 64 + m * 16 + lr;
                af[m] = as_bf(*(const u16x8*)(&Aa[row * 64 + (((kk * 4 + lg) ^ (lr & 7)) << 3)]));
            }
#pragma unroll
            for (int n = 0; n < 4; ++n) {
                int row = wc * 64 + n * 16 + lr;
                bfr[n] = as_bf(*(const u16x8*)(&Ba[row * 64 + (((kk * 4 + lg) ^ (lr & 7)) << 3)]));
            }
#pragma unroll
            for (int m = 0; m < 4; ++m)
#pragma unroll
                for (int n = 0; n < 4; ++n)
                    acc[m][n] = __builtin_amdgcn_mfma_f32_16x16x32_bf16(af[m], bfr[n], acc[m][n], 0, 0, 0);
        }
    }
    // epilogue: multiply by 1/rowsum, store f32
#pragma unroll
    for (int m = 0; m < 4; ++m) {
#pragma unroll
        for (int r = 0; r < 4; ++r) {
            int rloc = wr * 64 + m * 16 + lg * 4 + r;
            float rl = rl_s[rloc];
#pragma unroll
            for (int n = 0; n < 4; ++n)
                Out[(size_t)(q0 + rloc) * 1024 + e0 + wc * 64 + n * 16 + lr] = acc[m][n][r] * rl;
        }
    }
}

// ---------------------------------------------------------------------------
extern "C" void kernel_launch(void* const* d_in, const int* in_sizes, int n_in,
                              void* d_out, int out_size, void* d_ws, size_t ws_size,
                              hipStream_t stream) {
    const float* x  = (const float*)d_in[0];
    const float* Wq = (const float*)d_in[1];
    const float* Wk = (const float*)d_in[2];
    const float* Wv = (const float*)d_in[3];
    float* out = (float*)d_out;
    char* ws = (char*)d_ws;

    // ws_size is fixed across calls -> branch is deterministic.
    const bool big = (ws_size >= 125829120u);

    wt_kernel<<<dim3(16, 16, 3), 256, 0, stream>>>(Wq, Wk, Wv, (u16*)ws);

    if (big) {
        // merged-pair layout (120 MB): Xb pair aliases P0's first 16.8 MB
        // (dead until qk writes P0). 9 dispatches total.
        u16*   Wt  = (u16*)(ws);                   //   6,291,456
        u16*   Q0  = (u16*)(ws + 6291456);         //   8,388,608
        u16*   K0  = (u16*)(ws + 14680064);        //   8,388,608
        u16*   Q1  = (u16*)(ws + 23068672);        //   8,388,608
        u16*   K1  = (u16*)(ws + 31457280);        //   8,388,608
        u16*   V0  = (u16*)(ws + 39845888);        //   8,388,608
        u16*   V1  = (u16*)(ws + 48234496);        //   8,388,608
        u16*   P0  = (u16*)(ws + 56623104);        //  33,554,432
        u16*   P1  = (u16*)(ws + 90177536);        //  33,554,432
        float* plg = (float*)(ws + 123731968);     //   2,097,152  (= 125,829,120)
        u16*   XbA = P0;                           // alias: dead once qk runs
        u16*   XbB = P0 + 4194304;
        for (int p = 0; p < 2; ++p) {
            const float* x0 = x + (size_t)(2 * p) * 4194304;
            const float* x1 = x + (size_t)(2 * p + 1) * 4194304;
            float* o0 = out + (size_t)(2 * p) * 4194304;
            float* o1 = out + (size_t)(2 * p + 1) * 4194304;
            xconv<<<dim3(4096), 256, 0, stream>>>(x0, x1, XbA, XbB);
            qkv_gemm<<<dim3(1536), 256, 0, stream>>>(XbA, XbB, Wt, Q0, K0, V0, Q1, K1, V1, 2);
            qk_gemm<<<dim3(2048), 256, 0, stream>>>(Q0, K0, P0, Q1, K1, P1, plg, 2);
            pv_pair<<<dim3(512), 256, 0, stream>>>(P0, P1, V0, V1, plg, o0, o1);
        }
    } else {
        // fallback layout (109 MB): per-batch, Xb aliases the P buffer that
        // batch is about to write. 13 dispatches.
        u16*   Wt  = (u16*)(ws);
        u16*   Qb  = (u16*)(ws + 6291456);
        u16*   Kb  = (u16*)(ws + 14680064);
        u16*   V0  = (u16*)(ws + 23068672);
        u16*   V1  = (u16*)(ws + 31457280);
        u16*   P0  = (u16*)(ws + 39845888);
        u16*   P1  = (u16*)(ws + 73400320);
        float* plg = (float*)(ws + 106954752);
        for (int p = 0; p < 2; ++p) {
            const float* x0 = x + (size_t)(2 * p) * 4194304;
            const float* x1 = x + (size_t)(2 * p + 1) * 4194304;
            float* o0 = out + (size_t)(2 * p) * 4194304;
            float* o1 = out + (size_t)(2 * p + 1) * 4194304;
            xconv<<<dim3(2048), 256, 0, stream>>>(x0, x0, P0, P0);
            qkv_gemm<<<dim3(768), 256, 0, stream>>>(P0, P0, Wt, Qb, Kb, V0, Qb, Kb, V0, 1);
            qk_gemm<<<dim3(1024), 256, 0, stream>>>(Qb, Kb, P0, Qb, Kb, P0, plg, 1);
            xconv<<<dim3(2048), 256, 0, stream>>>(x1, x1, P1, P1);
            qkv_gemm<<<dim3(768), 256, 0, stream>>>(P1, P1, Wt, Qb, Kb, V1, Qb, Kb, V1, 1);
            qk_gemm<<<dim3(1024), 256, 0, stream>>>(Qb, Kb, P1, Qb, Kb, P1, plg + 262144, 1);
            pv_pair<<<dim3(512), 256, 0, stream>>>(P0, P1, V0, V1, plg, o0, o1);
        }
    }
}